// Round 8
// baseline (531.139 us; speedup 1.0000x reference)
//
#include <hip/hip_runtime.h>
#include <cstdio>
#include <cstdint>

typedef short bf16x8 __attribute__((ext_vector_type(8)));
typedef float f32x4 __attribute__((ext_vector_type(4)));

__device__ inline unsigned short f2bf(float f) {  // fp32 -> bf16 RNE
  unsigned u = __float_as_uint(f);
  u += 0x7fffu + ((u >> 16) & 1u);
  return (unsigned short)(u >> 16);
}
__device__ inline float bf2f(unsigned short h) {
  return __uint_as_float(((unsigned)h) << 16);
}

// ================= pre-pass: degree, norms, CSR build =================
// packed8[c][d]: per-(XCD-)copy histogram. high 24 bits = in-edge count,
// low 40 bits = sum(ew) in 2^-30 fixed point. A block updates copy
// blockIdx&7 -> 8x less line ping-pong (and XCD-local lines under
// round-robin dispatch). Returning atomic's old>>40 = edge's LOCAL rank
// within its copy; k_comb turns per-copy counts into exclusive bases so
// csr_fill needs no atomics.

__global__ void k_init8(unsigned long long* __restrict__ packed8, int n8) {
  int i = blockIdx.x * blockDim.x + threadIdx.x;
  if (i < n8) packed8[i] = 0ull;
}

__global__ void k_count_pack8(const int* __restrict__ dst, const float* __restrict__ ew,
                              unsigned long long* __restrict__ packed8,
                              int* __restrict__ rank, int N, int E) {
  int e = blockIdx.x * blockDim.x + threadIdx.x;
  if (e < E) {
    int copy = blockIdx.x & 7;
    unsigned long long q = (unsigned long long)(ew[e] * 1073741824.0f + 0.5f);
    unsigned long long old =
        atomicAdd(&packed8[(size_t)copy * N + dst[e]], (1ull << 40) | q);
    rank[e] = (int)(old >> 40);
  }
}

// combine 8 copies: exact total weighted degree (integer adds, bit-identical
// to a single-copy sum), per-copy exclusive count bases, total counts.
__global__ void k_comb(const unsigned long long* __restrict__ packed8,
                       int* __restrict__ cbase, int* __restrict__ ctot,
                       float* __restrict__ dinv, float* __restrict__ sn, int N) {
  int i = blockIdx.x * blockDim.x + threadIdx.x;
  if (i >= N) return;
  unsigned long long wsum = 0ull;
  int run = 0;
#pragma unroll
  for (int c = 0; c < 8; c++) {
    unsigned long long p = packed8[(size_t)c * N + i];
    cbase[(size_t)c * N + i] = run;
    run += (int)(p >> 40);
    wsum += (p & 0xFFFFFFFFFFull);
  }
  ctot[i] = run;
  double deg = 1.0 + (double)wsum * (1.0 / 1073741824.0);
  float r = (float)(1.0 / sqrt(deg));   // deg >= 1 always (self-loop)
  dinv[i] = r;
  sn[i] = r * r;
}

// exclusive scan of ctot -> rs[N]; 1024 elems / block
__global__ __launch_bounds__(256)
void k_scan1(const int* __restrict__ ctot, int* __restrict__ rs,
             int* __restrict__ bsum, int N) {
  __shared__ int sh[256];
  const int t = threadIdx.x;
  const int base = blockIdx.x * 1024;
  int v[4]; int s = 0;
#pragma unroll
  for (int j = 0; j < 4; j++) {
    int idx = base + t * 4 + j;
    v[j] = (idx < N) ? ctot[idx] : 0;
    s += v[j];
  }
  sh[t] = s;
  __syncthreads();
  for (int off = 1; off < 256; off <<= 1) {
    int x = (t >= off) ? sh[t - off] : 0;
    __syncthreads();
    sh[t] += x;
    __syncthreads();
  }
  int run = sh[t] - s;
#pragma unroll
  for (int j = 0; j < 4; j++) {
    int idx = base + t * 4 + j;
    if (idx < N) rs[idx] = run;
    run += v[j];
  }
  if (t == 255) bsum[blockIdx.x] = sh[255];
}

__global__ void k_scan2(int* __restrict__ bsum, int nb) {
  if (blockIdx.x == 0 && threadIdx.x == 0) {
    int run = 0;
    for (int i = 0; i < nb; i++) { int v = bsum[i]; bsum[i] = run; run += v; }
  }
}

__global__ void k_scan3(int* __restrict__ rs, const int* __restrict__ bsum, int N, int E) {
  int i = blockIdx.x * blockDim.x + threadIdx.x;
  if (i < N) rs[i] += bsum[i >> 10];
  if (i == 0) rs[N] = E;   // row-end sentinel
}

// no atomics: pos = rs[dst] + cbase[copy][dst] + local rank
__global__ void k_csr_fill(const int* __restrict__ src, const int* __restrict__ dst,
                           const float* __restrict__ ew, const float* __restrict__ dinv,
                           const int* __restrict__ rs, const int* __restrict__ cbase,
                           const int* __restrict__ rank,
                           int2* __restrict__ epack, int N, int E) {
  int e = blockIdx.x * blockDim.x + threadIdx.x;
  if (e >= E) return;
  int d = dst[e], s = src[e];
  int copy = blockIdx.x & 7;   // must match k_count_pack8's mapping (same grid)
  int pos = rs[d] + cbase[(size_t)copy * N + d] + rank[e];
  float w = dinv[s] * ew[e] * dinv[d];
  epack[pos] = make_int2(s, __float_as_int(w));
}

__global__ void k_zero_pool(double* __restrict__ psum, float* __restrict__ cnt, int B, int C) {
  int i = blockIdx.x * blockDim.x + threadIdx.x;
  if (i < B * C) psum[i] = 0.0;
  if (i < B) cnt[i] = 0.f;
}

// split W [K][D] fp32 -> transposed bf16 hi/lo [D][K]
__global__ void k_wsplit(const float* __restrict__ W, ushort* __restrict__ Th,
                         ushort* __restrict__ Tl, int K, int D) {
  int i = blockIdx.x * blockDim.x + threadIdx.x;
  if (i >= K * D) return;
  int k = i / D, n = i - k * D;
  float f = W[i];
  ushort h = f2bf(f);
  Th[(size_t)n * K + k] = h;
  Tl[(size_t)n * K + k] = f2bf(f - bf2f(h));
}

// fp32 -> bf16 (RNE), 4 elems/thread
__global__ void k_tobf(const float* __restrict__ X, ushort* __restrict__ Y, int n) {
  int base = (blockIdx.x * blockDim.x + threadIdx.x) * 4;
  if (base < n) {
    float4 v = *reinterpret_cast<const float4*>(X + base);
    ushort4 h;
    h.x = f2bf(v.x); h.y = f2bf(v.y); h.z = f2bf(v.z); h.w = f2bf(v.w);
    *reinterpret_cast<ushort4*>(Y + base) = h;
  }
}

// ================= CSR gather aggregation (bf16 in, bf16 hi/lo out) ======
// lanes/row = D/8; each lane handles 8 cols via one 16B load per gather.
// Edge loop unrolled x2 via int4 epack loads.

__device__ inline void bf8_fma(const int4 v, float w, float* acc) {
  acc[0] = fmaf(__uint_as_float((unsigned)v.x << 16), w, acc[0]);
  acc[1] = fmaf(__uint_as_float((unsigned)v.x & 0xffff0000u), w, acc[1]);
  acc[2] = fmaf(__uint_as_float((unsigned)v.y << 16), w, acc[2]);
  acc[3] = fmaf(__uint_as_float((unsigned)v.y & 0xffff0000u), w, acc[3]);
  acc[4] = fmaf(__uint_as_float((unsigned)v.z << 16), w, acc[4]);
  acc[5] = fmaf(__uint_as_float((unsigned)v.z & 0xffff0000u), w, acc[5]);
  acc[6] = fmaf(__uint_as_float((unsigned)v.w << 16), w, acc[6]);
  acc[7] = fmaf(__uint_as_float((unsigned)v.w & 0xffff0000u), w, acc[7]);
}

template<int LOG2L>
__global__ __launch_bounds__(256)
void k_aggregate_b(const ushort* __restrict__ Xb, const int* __restrict__ rs,
                   const int2* __restrict__ epack, const float* __restrict__ sn,
                   ushort* __restrict__ AH, ushort* __restrict__ AL, int N) {
  const int t = blockIdx.x * blockDim.x + threadIdx.x;
  const int row = t >> LOG2L;
  if (row >= N) return;
  const int L = 1 << LOG2L;
  const int D = L << 3;
  const int c = (t & (L - 1)) << 3;

  float acc[8];
  {
    int4 v = *reinterpret_cast<const int4*>(Xb + (size_t)row * D + c);
    float s = sn[row];
    acc[0] = s * __uint_as_float((unsigned)v.x << 16);
    acc[1] = s * __uint_as_float((unsigned)v.x & 0xffff0000u);
    acc[2] = s * __uint_as_float((unsigned)v.y << 16);
    acc[3] = s * __uint_as_float((unsigned)v.y & 0xffff0000u);
    acc[4] = s * __uint_as_float((unsigned)v.z << 16);
    acc[5] = s * __uint_as_float((unsigned)v.z & 0xffff0000u);
    acc[6] = s * __uint_as_float((unsigned)v.w << 16);
    acc[7] = s * __uint_as_float((unsigned)v.w & 0xffff0000u);
  }
  const int p0 = rs[row], pe = rs[row + 1];
  int i = p0;
  if ((i & 1) && i < pe) {   // peel to 16B-aligned pair index
    int2 e = epack[i];
    int4 v = *reinterpret_cast<const int4*>(Xb + (size_t)e.x * D + c);
    bf8_fma(v, __int_as_float(e.y), acc);
    i++;
  }
  for (; i + 2 <= pe; i += 2) {
    int4 e2 = *reinterpret_cast<const int4*>(&epack[i]);
    int4 v0 = *reinterpret_cast<const int4*>(Xb + (size_t)e2.x * D + c);
    int4 v1 = *reinterpret_cast<const int4*>(Xb + (size_t)e2.z * D + c);
    bf8_fma(v0, __int_as_float(e2.y), acc);
    bf8_fma(v1, __int_as_float(e2.w), acc);
  }
  if (i < pe) {
    int2 e = epack[i];
    int4 v = *reinterpret_cast<const int4*>(Xb + (size_t)e.x * D + c);
    bf8_fma(v, __int_as_float(e.y), acc);
  }
  ushort h[8], l[8];
#pragma unroll
  for (int j = 0; j < 8; j++) {
    h[j] = f2bf(acc[j]);
    l[j] = f2bf(acc[j] - bf2f(h[j]));
  }
  size_t o = (size_t)row * D + c;
  *reinterpret_cast<ushort4*>(AH + o)     = make_ushort4(h[0], h[1], h[2], h[3]);
  *reinterpret_cast<ushort4*>(AH + o + 4) = make_ushort4(h[4], h[5], h[6], h[7]);
  *reinterpret_cast<ushort4*>(AL + o)     = make_ushort4(l[0], l[1], l[2], l[3]);
  *reinterpret_cast<ushort4*>(AL + o + 4) = make_ushort4(l[4], l[5], l[6], l[7]);
}

// ================= split-bf16 MFMA GEMM: Y = relu(A @ W + b) =================
// OUTBF=1: write bf16; OUTBF=0: write fp32.

template<int KT, int NT, int OUTBF>
__global__ __launch_bounds__(256)
void k_gemm_mfma(const ushort* __restrict__ Ah, const ushort* __restrict__ Al,
                 const ushort* __restrict__ Bh, const ushort* __restrict__ Bl,
                 const float* __restrict__ bias, void* __restrict__ Yv,
                 int N, int D) {
  constexpr int PK = 72;  // padded row length (bf16) -> <=2-way LDS aliasing
  __shared__ __align__(16) ushort sAh[128 * PK];
  __shared__ __align__(16) ushort sAl[128 * PK];
  __shared__ __align__(16) ushort sBh[NT * PK];
  __shared__ __align__(16) ushort sBl[NT * PK];
  const int t = threadIdx.x;
  const int wave = t >> 6, lane = t & 63;
  const int quad = lane >> 4, l16 = lane & 15;
  const int m0 = blockIdx.y * 128;
  const int n0 = blockIdx.x * NT;

  f32x4 acc[2][NT / 16];
#pragma unroll
  for (int mi = 0; mi < 2; mi++)
#pragma unroll
    for (int ni = 0; ni < NT / 16; ni++) acc[mi][ni] = (f32x4){0.f, 0.f, 0.f, 0.f};

  for (int k0 = 0; k0 < KT; k0 += 64) {
    if (k0) __syncthreads();
#pragma unroll
    for (int it = 0; it < 4; it++) {
      int c = t + 256 * it;
      int row = c >> 3, kc = (c & 7) << 3;
      int gr = m0 + row; if (gr >= N) gr = N - 1;
      size_t gofs = (size_t)gr * KT + k0 + kc;
      *reinterpret_cast<int4*>(&sAh[row * PK + kc]) = *reinterpret_cast<const int4*>(Ah + gofs);
      *reinterpret_cast<int4*>(&sAl[row * PK + kc]) = *reinterpret_cast<const int4*>(Al + gofs);
    }
#pragma unroll
    for (int it = 0; it < NT / 32; it++) {
      int c = t + 256 * it;
      int row = c >> 3, kc = (c & 7) << 3;
      size_t gofs = (size_t)(n0 + row) * KT + k0 + kc;
      *reinterpret_cast<int4*>(&sBh[row * PK + kc]) = *reinterpret_cast<const int4*>(Bh + gofs);
      *reinterpret_cast<int4*>(&sBl[row * PK + kc]) = *reinterpret_cast<const int4*>(Bl + gofs);
    }
    __syncthreads();
#pragma unroll
    for (int ks = 0; ks < 2; ks++) {
      const int kk = ks * 32 + quad * 8;
      bf16x8 aH[2], aL[2];
#pragma unroll
      for (int mi = 0; mi < 2; mi++) {
        int r = wave * 32 + mi * 16 + l16;
        aH[mi] = *reinterpret_cast<const bf16x8*>(&sAh[r * PK + kk]);
        aL[mi] = *reinterpret_cast<const bf16x8*>(&sAl[r * PK + kk]);
      }
#pragma unroll
      for (int ni = 0; ni < NT / 16; ni++) {
        int r = ni * 16 + l16;
        bf16x8 bH = *reinterpret_cast<const bf16x8*>(&sBh[r * PK + kk]);
        bf16x8 bL = *reinterpret_cast<const bf16x8*>(&sBl[r * PK + kk]);
#pragma unroll
        for (int mi = 0; mi < 2; mi++) {
          acc[mi][ni] = __builtin_amdgcn_mfma_f32_16x16x32_bf16(aH[mi], bH, acc[mi][ni], 0, 0, 0);
          acc[mi][ni] = __builtin_amdgcn_mfma_f32_16x16x32_bf16(aH[mi], bL, acc[mi][ni], 0, 0, 0);
          acc[mi][ni] = __builtin_amdgcn_mfma_f32_16x16x32_bf16(aL[mi], bH, acc[mi][ni], 0, 0, 0);
        }
      }
    }
  }
  // epilogue: C/D layout col=lane&15, row=quad*4+reg
#pragma unroll
  for (int mi = 0; mi < 2; mi++) {
    int rb = m0 + wave * 32 + mi * 16 + quad * 4;
#pragma unroll
    for (int ni = 0; ni < NT / 16; ni++) {
      int col = n0 + ni * 16 + l16;
      float bv = bias[col];
#pragma unroll
      for (int r = 0; r < 4; r++) {
        int row = rb + r;
        if (row < N) {
          float y = fmaxf(acc[mi][ni][r] + bv, 0.f);
          if (OUTBF) ((ushort*)Yv)[(size_t)row * D + col] = f2bf(y);
          else       ((float*) Yv)[(size_t)row * D + col] = y;
        }
      }
    }
  }
}

// ================= pooling (sorted protein_batch) =================

__global__ void k_pool(const ushort* __restrict__ X3b, const float* __restrict__ feat,
                       const int* __restrict__ pb, double* __restrict__ psum,
                       int N, int D3, int F) {
  const int c = threadIdx.x;
  const int C = D3 + F;
  int i0 = blockIdx.x * 64;
  if (i0 >= N) return;
  int iend = i0 + 64; if (iend > N) iend = N;
  double acc = 0.0;
  int cur = pb[i0];
  for (int i = i0; i < iend; i++) {
    int b = pb[i];
    if (b != cur) {
      atomicAdd(&psum[(size_t)cur * C + c], acc);
      acc = 0.0; cur = b;
    }
    float v;
    if (c < D3) v = bf2f(X3b[(size_t)i * D3 + c]);
    else        v = feat[(size_t)i * F + (c - D3)];
    acc += (double)v;
  }
  atomicAdd(&psum[(size_t)cur * C + c], acc);
}

__global__ void k_count(const int* __restrict__ pb, float* __restrict__ cnt, int N) {
  int tchunk = blockIdx.x * blockDim.x + threadIdx.x;
  int i0 = tchunk * 64;
  if (i0 >= N) return;
  int iend = i0 + 64; if (iend > N) iend = N;
  float cacc = 0.f; int cur = pb[i0];
  for (int i = i0; i < iend; i++) {
    int b = pb[i];
    if (b != cur) { atomicAdd(&cnt[cur], cacc); cacc = 0.f; cur = b; }
    cacc += 1.f;
  }
  atomicAdd(&cnt[cur], cacc);
}

// ================= FC head =================

__global__ void k_gc(const double* __restrict__ psum, const float* __restrict__ cnt,
                     float* __restrict__ gc, int B, int C) {
  int i = blockIdx.x * blockDim.x + threadIdx.x;
  if (i < B * C) {
    int b = i / C;
    gc[i] = (float)psum[i] * (1.f / fmaxf(cnt[b], 1.f));
  }
}

__global__ __launch_bounds__(256)
void k_fc1(const float* __restrict__ gc, const float* __restrict__ Wf1,
           const float* __restrict__ bf1, float* __restrict__ hidden,
           int C, int Hh) {
  const int b = blockIdx.y;
  const int j = blockIdx.x * 256 + threadIdx.x;
  if (j >= Hh) return;
  const float* g = gc + (size_t)b * C;
  const float* w = Wf1 + j;
  float a0 = 0.f, a1 = 0.f, a2 = 0.f, a3 = 0.f;
  int c = 0;
  for (; c + 4 <= C; c += 4) {
    a0 = fmaf(g[c + 0], w[(size_t)(c + 0) * Hh], a0);
    a1 = fmaf(g[c + 1], w[(size_t)(c + 1) * Hh], a1);
    a2 = fmaf(g[c + 2], w[(size_t)(c + 2) * Hh], a2);
    a3 = fmaf(g[c + 3], w[(size_t)(c + 3) * Hh], a3);
  }
  for (; c < C; c++) a0 = fmaf(g[c], w[(size_t)c * Hh], a0);
  float r = ((a0 + a1) + (a2 + a3)) + bf1[j];
  hidden[(size_t)b * Hh + j] = fmaxf(r, 0.f);
}

__global__ void k_fc2(const float* __restrict__ hidden, const float* __restrict__ Wf2,
                      const float* __restrict__ bf2, float* __restrict__ out, int Hh) {
  int b = blockIdx.x;
  int lane = threadIdx.x;  // 64
  double s = 0.0;
  for (int j = lane; j < Hh; j += 64) s += (double)hidden[(size_t)b * Hh + j] * (double)Wf2[j];
#pragma unroll
  for (int off = 32; off > 0; off >>= 1) s += __shfl_down(s, off);
  if (lane == 0) out[b] = (float)s + bf2[0];
}

// ================= launch =================

extern "C" void kernel_launch(void* const* d_in, const int* in_sizes, int n_in,
                              void* d_out, int out_size, void* d_ws, size_t ws_size,
                              hipStream_t stream) {
  const float* feature = (const float*)d_in[0];
  const int*   eidx    = (const int*)  d_in[1];
  const float* weight  = (const float*)d_in[2];
  const int*   pb      = (const int*)  d_in[3];
  const float* W1  = (const float*)d_in[4];
  const float* b1  = (const float*)d_in[5];
  const float* W2  = (const float*)d_in[6];
  const float* b2  = (const float*)d_in[7];
  const float* W3  = (const float*)d_in[8];
  const float* b3  = (const float*)d_in[9];
  const float* Wf1 = (const float*)d_in[10];
  const float* bf1 = (const float*)d_in[11];
  const float* Wf2 = (const float*)d_in[12];
  const float* bf2 = (const float*)d_in[13];

  const int F  = in_sizes[5];          // 64
  const int D2 = in_sizes[7];          // 128
  const int D3 = in_sizes[9];          // 256
  const int Hh = in_sizes[11];         // 1024
  const int N  = in_sizes[0] / F;      // 100000
  const int E  = in_sizes[1] / 2;      // 1200000
  const int B  = out_size;             // 256
  const int C  = D3 + F;               // 320

  const int* srcp = eidx;
  const int* dstp = eidx + E;
  const int nscan = (N + 1023) / 1024;

  auto al = [](size_t x) { return (x + 255) & ~(size_t)255; };
  size_t off = 0;
  auto alloc = [&](size_t bytes) { size_t o = off; off += al(bytes); return o; };
  size_t o_pack  = alloc((size_t)N * 8 * 8);     // 8 copies
  size_t o_cbase = alloc((size_t)N * 8 * 4);     // per-copy exclusive bases
  size_t o_ctot  = alloc((size_t)N * 4);
  size_t o_dinv  = alloc((size_t)N * 4);
  size_t o_sn    = alloc((size_t)N * 4);
  size_t o_rs    = alloc((size_t)(N + 1) * 4);
  size_t o_rank  = alloc((size_t)E * 4);
  size_t o_bsum  = alloc((size_t)nscan * 4);
  size_t o_epack = alloc((size_t)E * 8);
  size_t o_featb = alloc((size_t)N * F  * 2);
  size_t o_x1b   = alloc((size_t)N * F  * 2);
  size_t o_x2b   = alloc((size_t)N * D2 * 2);
  size_t o_x3b   = alloc((size_t)N * D3 * 2);
  size_t o_aggh  = alloc((size_t)N * D2 * 2);   // bf16 hi (max K = 128)
  size_t o_aggl  = alloc((size_t)N * D2 * 2);   // bf16 lo
  size_t o_w1h   = alloc((size_t)F  * F  * 2);
  size_t o_w1l   = alloc((size_t)F  * F  * 2);
  size_t o_w2h   = alloc((size_t)F  * D2 * 2);
  size_t o_w2l   = alloc((size_t)F  * D2 * 2);
  size_t o_w3h   = alloc((size_t)D2 * D3 * 2);
  size_t o_w3l   = alloc((size_t)D2 * D3 * 2);
  size_t o_psum  = alloc((size_t)B * C * 8);
  size_t o_gc    = alloc((size_t)B * C * 4);
  size_t o_gcnt  = alloc((size_t)B * 4);
  size_t o_hid   = alloc((size_t)B * Hh * 4);
  if (off > ws_size) {
    fprintf(stderr, "kernel_launch: workspace too small: need %zu, have %zu\n", off, ws_size);
    return;
  }

  char* ws = (char*)d_ws;
  unsigned long long* packed8 = (unsigned long long*)(ws + o_pack);
  int*    cbase = (int*)  (ws + o_cbase);
  int*    ctot  = (int*)  (ws + o_ctot);
  float*  dinv  = (float*)(ws + o_dinv);
  float*  sn    = (float*)(ws + o_sn);
  int*    rs    = (int*)  (ws + o_rs);
  int*    rank  = (int*)  (ws + o_rank);
  int*    bsum  = (int*)  (ws + o_bsum);
  int2*   epack = (int2*) (ws + o_epack);
  ushort* featb = (ushort*)(ws + o_featb);
  ushort* x1b   = (ushort*)(ws + o_x1b);
  ushort* x2b   = (ushort*)(ws + o_x2b);
  ushort* x3b   = (ushort*)(ws + o_x3b);
  ushort* aggh  = (ushort*)(ws + o_aggh);
  ushort* aggl  = (ushort*)(ws + o_aggl);
  ushort* w1h   = (ushort*)(ws + o_w1h);
  ushort* w1l   = (ushort*)(ws + o_w1l);
  ushort* w2h   = (ushort*)(ws + o_w2h);
  ushort* w2l   = (ushort*)(ws + o_w2l);
  ushort* w3h   = (ushort*)(ws + o_w3h);
  ushort* w3l   = (ushort*)(ws + o_w3l);
  double* psum  = (double*)(ws + o_psum);
  float*  gcbuf = (float*)(ws + o_gc);
  float*  gcnt  = (float*)(ws + o_gcnt);
  float*  hid   = (float*)(ws + o_hid);
  float*  out   = (float*)d_out;

  const int egrid = (E + 255) / 256;

  // ---- pre-pass + CSR build + weight split ----
  k_init8      <<<(8 * N + 255) / 256, 256, 0, stream>>>(packed8, 8 * N);
  k_count_pack8<<<egrid, 256, 0, stream>>>(dstp, weight, packed8, rank, N, E);
  k_comb       <<<(N + 255) / 256, 256, 0, stream>>>(packed8, cbase, ctot, dinv, sn, N);
  k_scan1      <<<nscan, 256, 0, stream>>>(ctot, rs, bsum, N);
  k_scan2      <<<1, 64, 0, stream>>>(bsum, nscan);
  k_scan3      <<<(N + 255) / 256, 256, 0, stream>>>(rs, bsum, N, E);
  k_csr_fill   <<<egrid, 256, 0, stream>>>(srcp, dstp, weight, dinv, rs, cbase, rank, epack, N, E);
  k_zero_pool  <<<(B * C + 255) / 256, 256, 0, stream>>>(psum, gcnt, B, C);
  k_tobf       <<<(N * F / 4 + 255) / 256, 256, 0, stream>>>(feature, featb, N * F);
  k_wsplit     <<<(F  * F  + 255) / 256, 256, 0, stream>>>(W1, w1h, w1l, F,  F);
  k_wsplit     <<<(F  * D2 + 255) / 256, 256, 0, stream>>>(W2, w2h, w2l, F,  D2);
  k_wsplit     <<<(D2 * D3 + 255) / 256, 256, 0, stream>>>(W3, w3h, w3l, D2, D3);

  const int gy = (N + 127) / 128;

  // ---- layer 1: agg(featb)[N,64] @ W1[64,64] -> x1b (bf16) ----
  {
    int tot = N * (F / 8);
    k_aggregate_b<3><<<(tot + 255) / 256, 256, 0, stream>>>(featb, rs, epack, sn, aggh, aggl, N);
    dim3 g(1, gy);
    k_gemm_mfma<64, 64, 1><<<g, 256, 0, stream>>>(aggh, aggl, w1h, w1l, b1, x1b, N, F);
  }
  // ---- layer 2: agg(x1b)[N,64] @ W2[64,128] -> x2b (bf16) ----
  {
    int tot = N * (F / 8);
    k_aggregate_b<3><<<(tot + 255) / 256, 256, 0, stream>>>(x1b, rs, epack, sn, aggh, aggl, N);
    dim3 g(1, gy);
    k_gemm_mfma<64, 128, 1><<<g, 256, 0, stream>>>(aggh, aggl, w2h, w2l, b2, x2b, N, D2);
  }
  // ---- layer 3: agg(x2b)[N,128] @ W3[128,256] -> x3b (bf16) ----
  {
    int tot = N * (D2 / 8);
    k_aggregate_b<4><<<(tot + 255) / 256, 256, 0, stream>>>(x2b, rs, epack, sn, aggh, aggl, N);
    dim3 g(2, gy);
    k_gemm_mfma<128, 128, 1><<<g, 256, 0, stream>>>(aggh, aggl, w3h, w3l, b3, x3b, N, D3);
  }

  // ---- pooling + head ----
  k_count<<<((N + 63) / 64 + 255) / 256, 256, 0, stream>>>(pb, gcnt, N);
  k_pool <<<(N + 63) / 64, C, 0, stream>>>(x3b, feature, pb, psum, N, D3, F);
  k_gc   <<<(B * C + 255) / 256, 256, 0, stream>>>(psum, gcnt, gcbuf, B, C);
  {
    dim3 g((Hh + 255) / 256, B);
    k_fc1<<<g, 256, 0, stream>>>(gcbuf, Wf1, bf1, hid, C, Hh);
  }
  k_fc2  <<<B, 64, 0, stream>>>(hid, Wf2, bf2, out, Hh);
}

// Round 9
// 492.402 us; speedup vs baseline: 1.0787x; 1.0787x over previous
//
#include <hip/hip_runtime.h>
#include <cstdio>
#include <cstdint>

typedef _Float16 f16x8 __attribute__((ext_vector_type(8)));
typedef float f32x4 __attribute__((ext_vector_type(4)));

__device__ inline unsigned short f2bf(float f) {  // fp32 -> bf16 RNE
  unsigned u = __float_as_uint(f);
  u += 0x7fffu + ((u >> 16) & 1u);
  return (unsigned short)(u >> 16);
}
__device__ inline float bf2f(unsigned short h) {
  return __uint_as_float(((unsigned)h) << 16);
}
__device__ inline unsigned short f2h(float f) {   // fp32 -> fp16 RNE (bits)
  union { _Float16 h; unsigned short u; } cv;
  cv.h = (_Float16)f;
  return cv.u;
}

// ================= pre-pass: degree, norms, CSR build =================
// packed[d]: high 24 bits = in-edge count, low 40 bits = sum(ew) in 2^-30
// fixed point. Returning atomic's old>>40 = edge's rank within its dst row
// -> csr_fill needs no atomics. (R8 showed 8-way privatization is neutral:
// device RMW throughput ~21G/s is the floor regardless of contention.)

__global__ void k_init(unsigned long long* __restrict__ packed, int N) {
  int i = blockIdx.x * blockDim.x + threadIdx.x;
  if (i < N) packed[i] = 0ull;
}

__global__ void k_count_pack(const int* __restrict__ dst, const float* __restrict__ ew,
                             unsigned long long* __restrict__ packed,
                             int* __restrict__ rank, int E) {
  int e = blockIdx.x * blockDim.x + threadIdx.x;
  if (e < E) {
    unsigned long long q = (unsigned long long)(ew[e] * 1073741824.0f + 0.5f);
    unsigned long long old = atomicAdd(&packed[dst[e]], (1ull << 40) | q);
    rank[e] = (int)(old >> 40);
  }
}

__global__ void k_dinv(const unsigned long long* __restrict__ packed,
                       float* __restrict__ dinv, float* __restrict__ selfnorm, int N) {
  int i = blockIdx.x * blockDim.x + threadIdx.x;
  if (i < N) {
    unsigned long long p = packed[i];
    double deg = 1.0 + (double)(p & 0xFFFFFFFFFFull) * (1.0 / 1073741824.0);
    float r = (float)(1.0 / sqrt(deg));   // deg >= 1 always (self-loop)
    dinv[i] = r;
    selfnorm[i] = r * r;
  }
}

// exclusive scan of cnt (= packed>>40) -> rs[N]; 1024 elems / block
__global__ __launch_bounds__(256)
void k_scan1(const unsigned long long* __restrict__ packed, int* __restrict__ rs,
             int* __restrict__ bsum, int N) {
  __shared__ int sh[256];
  const int t = threadIdx.x;
  const int base = blockIdx.x * 1024;
  int v[4]; int s = 0;
#pragma unroll
  for (int j = 0; j < 4; j++) {
    int idx = base + t * 4 + j;
    v[j] = (idx < N) ? (int)(packed[idx] >> 40) : 0;
    s += v[j];
  }
  sh[t] = s;
  __syncthreads();
  for (int off = 1; off < 256; off <<= 1) {
    int x = (t >= off) ? sh[t - off] : 0;
    __syncthreads();
    sh[t] += x;
    __syncthreads();
  }
  int run = sh[t] - s;
#pragma unroll
  for (int j = 0; j < 4; j++) {
    int idx = base + t * 4 + j;
    if (idx < N) rs[idx] = run;
    run += v[j];
  }
  if (t == 255) bsum[blockIdx.x] = sh[255];
}

__global__ void k_scan2(int* __restrict__ bsum, int nb) {
  if (blockIdx.x == 0 && threadIdx.x == 0) {
    int run = 0;
    for (int i = 0; i < nb; i++) { int v = bsum[i]; bsum[i] = run; run += v; }
  }
}

__global__ void k_scan3(int* __restrict__ rs, const int* __restrict__ bsum, int N, int E) {
  int i = blockIdx.x * blockDim.x + threadIdx.x;
  if (i < N) rs[i] += bsum[i >> 10];
  if (i == 0) rs[N] = E;   // row-end sentinel
}

// no atomics: pos = rs[dst] + rank (rank captured in k_count_pack)
__global__ void k_csr_fill(const int* __restrict__ src, const int* __restrict__ dst,
                           const float* __restrict__ ew, const float* __restrict__ dinv,
                           const int* __restrict__ rs, const int* __restrict__ rank,
                           int2* __restrict__ epack, int E) {
  int e = blockIdx.x * blockDim.x + threadIdx.x;
  if (e >= E) return;
  int d = dst[e], s = src[e];
  int pos = rs[d] + rank[e];
  float w = dinv[s] * ew[e] * dinv[d];
  epack[pos] = make_int2(s, __float_as_int(w));
}

__global__ void k_zero_pool(double* __restrict__ psum, float* __restrict__ cnt, int B, int C) {
  int i = blockIdx.x * blockDim.x + threadIdx.x;
  if (i < B * C) psum[i] = 0.0;
  if (i < B) cnt[i] = 0.f;
}

// W [K][D] fp32 -> transposed fp16 [D][K]
__global__ void k_wh(const float* __restrict__ W, ushort* __restrict__ Th, int K, int D) {
  int i = blockIdx.x * blockDim.x + threadIdx.x;
  if (i >= K * D) return;
  int k = i / D, n = i - k * D;
  Th[(size_t)n * K + k] = f2h(W[i]);
}

// fp32 -> bf16 (RNE), 4 elems/thread
__global__ void k_tobf(const float* __restrict__ X, ushort* __restrict__ Y, int n) {
  int base = (blockIdx.x * blockDim.x + threadIdx.x) * 4;
  if (base < n) {
    float4 v = *reinterpret_cast<const float4*>(X + base);
    ushort4 h;
    h.x = f2bf(v.x); h.y = f2bf(v.y); h.z = f2bf(v.z); h.w = f2bf(v.w);
    *reinterpret_cast<ushort4*>(Y + base) = h;
  }
}

// ================= CSR gather aggregation (bf16 in, fp16 out) ======
// lanes/row = D/8; each lane handles 8 cols via one 16B load per gather.
// Edge loop unrolled x2 via int4 epack loads.

__device__ inline void bf8_fma(const int4 v, float w, float* acc) {
  acc[0] = fmaf(__uint_as_float((unsigned)v.x << 16), w, acc[0]);
  acc[1] = fmaf(__uint_as_float((unsigned)v.x & 0xffff0000u), w, acc[1]);
  acc[2] = fmaf(__uint_as_float((unsigned)v.y << 16), w, acc[2]);
  acc[3] = fmaf(__uint_as_float((unsigned)v.y & 0xffff0000u), w, acc[3]);
  acc[4] = fmaf(__uint_as_float((unsigned)v.z << 16), w, acc[4]);
  acc[5] = fmaf(__uint_as_float((unsigned)v.z & 0xffff0000u), w, acc[5]);
  acc[6] = fmaf(__uint_as_float((unsigned)v.w << 16), w, acc[6]);
  acc[7] = fmaf(__uint_as_float((unsigned)v.w & 0xffff0000u), w, acc[7]);
}

template<int LOG2L>
__global__ __launch_bounds__(256)
void k_aggregate_b(const ushort* __restrict__ Xb, const int* __restrict__ rs,
                   const int2* __restrict__ epack, const float* __restrict__ sn,
                   ushort* __restrict__ AH, int N) {
  const int t = blockIdx.x * blockDim.x + threadIdx.x;
  const int row = t >> LOG2L;
  if (row >= N) return;
  const int L = 1 << LOG2L;
  const int D = L << 3;
  const int c = (t & (L - 1)) << 3;

  float acc[8];
  {
    int4 v = *reinterpret_cast<const int4*>(Xb + (size_t)row * D + c);
    float s = sn[row];
    acc[0] = s * __uint_as_float((unsigned)v.x << 16);
    acc[1] = s * __uint_as_float((unsigned)v.x & 0xffff0000u);
    acc[2] = s * __uint_as_float((unsigned)v.y << 16);
    acc[3] = s * __uint_as_float((unsigned)v.y & 0xffff0000u);
    acc[4] = s * __uint_as_float((unsigned)v.z << 16);
    acc[5] = s * __uint_as_float((unsigned)v.z & 0xffff0000u);
    acc[6] = s * __uint_as_float((unsigned)v.w << 16);
    acc[7] = s * __uint_as_float((unsigned)v.w & 0xffff0000u);
  }
  const int p0 = rs[row], pe = rs[row + 1];
  int i = p0;
  if ((i & 1) && i < pe) {   // peel to 16B-aligned pair index
    int2 e = epack[i];
    int4 v = *reinterpret_cast<const int4*>(Xb + (size_t)e.x * D + c);
    bf8_fma(v, __int_as_float(e.y), acc);
    i++;
  }
  for (; i + 2 <= pe; i += 2) {
    int4 e2 = *reinterpret_cast<const int4*>(&epack[i]);
    int4 v0 = *reinterpret_cast<const int4*>(Xb + (size_t)e2.x * D + c);
    int4 v1 = *reinterpret_cast<const int4*>(Xb + (size_t)e2.z * D + c);
    bf8_fma(v0, __int_as_float(e2.y), acc);
    bf8_fma(v1, __int_as_float(e2.w), acc);
  }
  if (i < pe) {
    int2 e = epack[i];
    int4 v = *reinterpret_cast<const int4*>(Xb + (size_t)e.x * D + c);
    bf8_fma(v, __int_as_float(e.y), acc);
  }
  ushort h[8];
#pragma unroll
  for (int j = 0; j < 8; j++) h[j] = f2h(acc[j]);
  size_t o = (size_t)row * D + c;
  *reinterpret_cast<ushort4*>(AH + o)     = make_ushort4(h[0], h[1], h[2], h[3]);
  *reinterpret_cast<ushort4*>(AH + o + 4) = make_ushort4(h[4], h[5], h[6], h[7]);
}

// ================= fp16 MFMA GEMM: Y = relu(A @ W + b), bf16 out ==========
// A fp16 [N][KT]; W transposed fp16 [D][KT]. Single MFMA pass, fp32 acc.

template<int KT, int NT>
__global__ __launch_bounds__(256)
void k_gemm_mfma(const ushort* __restrict__ Ah, const ushort* __restrict__ Bh,
                 const float* __restrict__ bias, ushort* __restrict__ Y,
                 int N, int D) {
  constexpr int PK = 72;  // padded row length -> <=2-way LDS aliasing
  __shared__ __align__(16) ushort sAh[128 * PK];
  __shared__ __align__(16) ushort sBh[NT * PK];
  const int t = threadIdx.x;
  const int wave = t >> 6, lane = t & 63;
  const int quad = lane >> 4, l16 = lane & 15;
  const int m0 = blockIdx.y * 128;
  const int n0 = blockIdx.x * NT;

  f32x4 acc[2][NT / 16];
#pragma unroll
  for (int mi = 0; mi < 2; mi++)
#pragma unroll
    for (int ni = 0; ni < NT / 16; ni++) acc[mi][ni] = (f32x4){0.f, 0.f, 0.f, 0.f};

  for (int k0 = 0; k0 < KT; k0 += 64) {
    if (k0) __syncthreads();
#pragma unroll
    for (int it = 0; it < 4; it++) {     // A: 128 rows x 64 k = 1024 16B-chunks
      int c = t + 256 * it;
      int row = c >> 3, kc = (c & 7) << 3;
      int gr = m0 + row; if (gr >= N) gr = N - 1;
      *reinterpret_cast<int4*>(&sAh[row * PK + kc]) =
          *reinterpret_cast<const int4*>(Ah + (size_t)gr * KT + k0 + kc);
    }
#pragma unroll
    for (int it = 0; it < NT / 32; it++) {  // B: NT rows x 64 k
      int c = t + 256 * it;
      int row = c >> 3, kc = (c & 7) << 3;
      *reinterpret_cast<int4*>(&sBh[row * PK + kc]) =
          *reinterpret_cast<const int4*>(Bh + (size_t)(n0 + row) * KT + k0 + kc);
    }
    __syncthreads();
#pragma unroll
    for (int ks = 0; ks < 2; ks++) {
      const int kk = ks * 32 + quad * 8;
      f16x8 aH[2];
#pragma unroll
      for (int mi = 0; mi < 2; mi++) {
        int r = wave * 32 + mi * 16 + l16;
        aH[mi] = *reinterpret_cast<const f16x8*>(&sAh[r * PK + kk]);
      }
#pragma unroll
      for (int ni = 0; ni < NT / 16; ni++) {
        int r = ni * 16 + l16;
        f16x8 bH = *reinterpret_cast<const f16x8*>(&sBh[r * PK + kk]);
#pragma unroll
        for (int mi = 0; mi < 2; mi++)
          acc[mi][ni] = __builtin_amdgcn_mfma_f32_16x16x32_f16(aH[mi], bH, acc[mi][ni], 0, 0, 0);
      }
    }
  }
  // epilogue: C/D layout col=lane&15, row=quad*4+reg; write bf16
#pragma unroll
  for (int mi = 0; mi < 2; mi++) {
    int rb = m0 + wave * 32 + mi * 16 + quad * 4;
#pragma unroll
    for (int ni = 0; ni < NT / 16; ni++) {
      int col = n0 + ni * 16 + l16;
      float bv = bias[col];
#pragma unroll
      for (int r = 0; r < 4; r++) {
        int row = rb + r;
        if (row < N)
          Y[(size_t)row * D + col] = f2bf(fmaxf(acc[mi][ni][r] + bv, 0.f));
      }
    }
  }
}

// ================= pooling (sorted protein_batch) =================

__global__ void k_pool(const ushort* __restrict__ X3b, const float* __restrict__ feat,
                       const int* __restrict__ pb, double* __restrict__ psum,
                       int N, int D3, int F) {
  const int c = threadIdx.x;
  const int C = D3 + F;
  int i0 = blockIdx.x * 64;
  if (i0 >= N) return;
  int iend = i0 + 64; if (iend > N) iend = N;
  double acc = 0.0;
  int cur = pb[i0];
  for (int i = i0; i < iend; i++) {
    int b = pb[i];
    if (b != cur) {
      atomicAdd(&psum[(size_t)cur * C + c], acc);
      acc = 0.0; cur = b;
    }
    float v;
    if (c < D3) v = bf2f(X3b[(size_t)i * D3 + c]);
    else        v = feat[(size_t)i * F + (c - D3)];
    acc += (double)v;
  }
  atomicAdd(&psum[(size_t)cur * C + c], acc);
}

__global__ void k_count(const int* __restrict__ pb, float* __restrict__ cnt, int N) {
  int tchunk = blockIdx.x * blockDim.x + threadIdx.x;
  int i0 = tchunk * 64;
  if (i0 >= N) return;
  int iend = i0 + 64; if (iend > N) iend = N;
  float cacc = 0.f; int cur = pb[i0];
  for (int i = i0; i < iend; i++) {
    int b = pb[i];
    if (b != cur) { atomicAdd(&cnt[cur], cacc); cacc = 0.f; cur = b; }
    cacc += 1.f;
  }
  atomicAdd(&cnt[cur], cacc);
}

// ================= FC head =================

__global__ void k_gc(const double* __restrict__ psum, const float* __restrict__ cnt,
                     float* __restrict__ gc, int B, int C) {
  int i = blockIdx.x * blockDim.x + threadIdx.x;
  if (i < B * C) {
    int b = i / C;
    gc[i] = (float)psum[i] * (1.f / fmaxf(cnt[b], 1.f));
  }
}

__global__ __launch_bounds__(256)
void k_fc1(const float* __restrict__ gc, const float* __restrict__ Wf1,
           const float* __restrict__ bf1, float* __restrict__ hidden,
           int C, int Hh) {
  const int b = blockIdx.y;
  const int j = blockIdx.x * 256 + threadIdx.x;
  if (j >= Hh) return;
  const float* g = gc + (size_t)b * C;
  const float* w = Wf1 + j;
  float a0 = 0.f, a1 = 0.f, a2 = 0.f, a3 = 0.f;
  int c = 0;
  for (; c + 4 <= C; c += 4) {
    a0 = fmaf(g[c + 0], w[(size_t)(c + 0) * Hh], a0);
    a1 = fmaf(g[c + 1], w[(size_t)(c + 1) * Hh], a1);
    a2 = fmaf(g[c + 2], w[(size_t)(c + 2) * Hh], a2);
    a3 = fmaf(g[c + 3], w[(size_t)(c + 3) * Hh], a3);
  }
  for (; c < C; c++) a0 = fmaf(g[c], w[(size_t)c * Hh], a0);
  float r = ((a0 + a1) + (a2 + a3)) + bf1[j];
  hidden[(size_t)b * Hh + j] = fmaxf(r, 0.f);
}

__global__ void k_fc2(const float* __restrict__ hidden, const float* __restrict__ Wf2,
                      const float* __restrict__ bf2, float* __restrict__ out, int Hh) {
  int b = blockIdx.x;
  int lane = threadIdx.x;  // 64
  double s = 0.0;
  for (int j = lane; j < Hh; j += 64) s += (double)hidden[(size_t)b * Hh + j] * (double)Wf2[j];
#pragma unroll
  for (int off = 32; off > 0; off >>= 1) s += __shfl_down(s, off);
  if (lane == 0) out[b] = (float)s + bf2[0];
}

// ================= launch =================

extern "C" void kernel_launch(void* const* d_in, const int* in_sizes, int n_in,
                              void* d_out, int out_size, void* d_ws, size_t ws_size,
                              hipStream_t stream) {
  const float* feature = (const float*)d_in[0];
  const int*   eidx    = (const int*)  d_in[1];
  const float* weight  = (const float*)d_in[2];
  const int*   pb      = (const int*)  d_in[3];
  const float* W1  = (const float*)d_in[4];
  const float* b1  = (const float*)d_in[5];
  const float* W2  = (const float*)d_in[6];
  const float* b2  = (const float*)d_in[7];
  const float* W3  = (const float*)d_in[8];
  const float* b3  = (const float*)d_in[9];
  const float* Wf1 = (const float*)d_in[10];
  const float* bf1 = (const float*)d_in[11];
  const float* Wf2 = (const float*)d_in[12];
  const float* bf2 = (const float*)d_in[13];

  const int F  = in_sizes[5];          // 64
  const int D2 = in_sizes[7];          // 128
  const int D3 = in_sizes[9];          // 256
  const int Hh = in_sizes[11];         // 1024
  const int N  = in_sizes[0] / F;      // 100000
  const int E  = in_sizes[1] / 2;      // 1200000
  const int B  = out_size;             // 256
  const int C  = D3 + F;               // 320

  const int* srcp = eidx;
  const int* dstp = eidx + E;
  const int nscan = (N + 1023) / 1024;

  auto al = [](size_t x) { return (x + 255) & ~(size_t)255; };
  size_t off = 0;
  auto alloc = [&](size_t bytes) { size_t o = off; off += al(bytes); return o; };
  size_t o_pack  = alloc((size_t)N * 8);
  size_t o_dinv  = alloc((size_t)N * 4);
  size_t o_sn    = alloc((size_t)N * 4);
  size_t o_rs    = alloc((size_t)(N + 1) * 4);
  size_t o_rank  = alloc((size_t)E * 4);
  size_t o_bsum  = alloc((size_t)nscan * 4);
  size_t o_epack = alloc((size_t)E * 8);
  size_t o_featb = alloc((size_t)N * F  * 2);
  size_t o_x1b   = alloc((size_t)N * F  * 2);
  size_t o_x2b   = alloc((size_t)N * D2 * 2);
  size_t o_x3b   = alloc((size_t)N * D3 * 2);
  size_t o_aggh  = alloc((size_t)N * D2 * 2);   // fp16 (max K = 128)
  size_t o_w1h   = alloc((size_t)F  * F  * 2);
  size_t o_w2h   = alloc((size_t)F  * D2 * 2);
  size_t o_w3h   = alloc((size_t)D2 * D3 * 2);
  size_t o_psum  = alloc((size_t)B * C * 8);
  size_t o_gc    = alloc((size_t)B * C * 4);
  size_t o_gcnt  = alloc((size_t)B * 4);
  size_t o_hid   = alloc((size_t)B * Hh * 4);
  if (off > ws_size) {
    fprintf(stderr, "kernel_launch: workspace too small: need %zu, have %zu\n", off, ws_size);
    return;
  }

  char* ws = (char*)d_ws;
  unsigned long long* packed = (unsigned long long*)(ws + o_pack);
  float*  dinv  = (float*)(ws + o_dinv);
  float*  sn    = (float*)(ws + o_sn);
  int*    rs    = (int*)  (ws + o_rs);
  int*    rank  = (int*)  (ws + o_rank);
  int*    bsum  = (int*)  (ws + o_bsum);
  int2*   epack = (int2*) (ws + o_epack);
  ushort* featb = (ushort*)(ws + o_featb);
  ushort* x1b   = (ushort*)(ws + o_x1b);
  ushort* x2b   = (ushort*)(ws + o_x2b);
  ushort* x3b   = (ushort*)(ws + o_x3b);
  ushort* aggh  = (ushort*)(ws + o_aggh);
  ushort* w1h   = (ushort*)(ws + o_w1h);
  ushort* w2h   = (ushort*)(ws + o_w2h);
  ushort* w3h   = (ushort*)(ws + o_w3h);
  double* psum  = (double*)(ws + o_psum);
  float*  gcbuf = (float*)(ws + o_gc);
  float*  gcnt  = (float*)(ws + o_gcnt);
  float*  hid   = (float*)(ws + o_hid);
  float*  out   = (float*)d_out;

  // ---- pre-pass + CSR build + weight convert ----
  k_init       <<<(N + 255) / 256, 256, 0, stream>>>(packed, N);
  k_count_pack <<<(E + 255) / 256, 256, 0, stream>>>(dstp, weight, packed, rank, E);
  k_dinv       <<<(N + 255) / 256, 256, 0, stream>>>(packed, dinv, sn, N);
  k_scan1      <<<nscan, 256, 0, stream>>>(packed, rs, bsum, N);
  k_scan2      <<<1, 64, 0, stream>>>(bsum, nscan);
  k_scan3      <<<(N + 255) / 256, 256, 0, stream>>>(rs, bsum, N, E);
  k_csr_fill   <<<(E + 255) / 256, 256, 0, stream>>>(srcp, dstp, weight, dinv, rs, rank, epack, E);
  k_zero_pool  <<<(B * C + 255) / 256, 256, 0, stream>>>(psum, gcnt, B, C);
  k_tobf       <<<(N * F / 4 + 255) / 256, 256, 0, stream>>>(feature, featb, N * F);
  k_wh         <<<(F  * F  + 255) / 256, 256, 0, stream>>>(W1, w1h, F,  F);
  k_wh         <<<(F  * D2 + 255) / 256, 256, 0, stream>>>(W2, w2h, F,  D2);
  k_wh         <<<(D2 * D3 + 255) / 256, 256, 0, stream>>>(W3, w3h, D2, D3);

  const int gy = (N + 127) / 128;

  // ---- layer 1: agg(featb)[N,64] @ W1[64,64] -> x1b (bf16) ----
  {
    int tot = N * (F / 8);
    k_aggregate_b<3><<<(tot + 255) / 256, 256, 0, stream>>>(featb, rs, epack, sn, aggh, N);
    dim3 g(1, gy);
    k_gemm_mfma<64, 64><<<g, 256, 0, stream>>>(aggh, w1h, b1, x1b, N, F);
  }
  // ---- layer 2: agg(x1b)[N,64] @ W2[64,128] -> x2b (bf16) ----
  {
    int tot = N * (F / 8);
    k_aggregate_b<3><<<(tot + 255) / 256, 256, 0, stream>>>(x1b, rs, epack, sn, aggh, N);
    dim3 g(1, gy);
    k_gemm_mfma<64, 128><<<g, 256, 0, stream>>>(aggh, w2h, b2, x2b, N, D2);
  }
  // ---- layer 3: agg(x2b)[N,128] @ W3[128,256] -> x3b (bf16) ----
  {
    int tot = N * (D2 / 8);
    k_aggregate_b<4><<<(tot + 255) / 256, 256, 0, stream>>>(x2b, rs, epack, sn, aggh, N);
    dim3 g(2, gy);
    k_gemm_mfma<128, 128><<<g, 256, 0, stream>>>(aggh, w3h, b3, x3b, N, D3);
  }

  // ---- pooling + head ----
  k_count<<<((N + 63) / 64 + 255) / 256, 256, 0, stream>>>(pb, gcnt, N);
  k_pool <<<(N + 63) / 64, C, 0, stream>>>(x3b, feature, pb, psum, N, D3, F);
  k_gc   <<<(B * C + 255) / 256, 256, 0, stream>>>(psum, gcnt, gcbuf, B, C);
  {
    dim3 g((Hh + 255) / 256, B);
    k_fc1<<<g, 256, 0, stream>>>(gcbuf, Wf1, bf1, hid, C, Hh);
  }
  k_fc2  <<<B, 64, 0, stream>>>(hid, Wf2, bf2, out, Hh);
}

// Round 10
// 457.877 us; speedup vs baseline: 1.1600x; 1.0754x over previous
//
#include <hip/hip_runtime.h>
#include <cstdio>
#include <cstdint>

typedef _Float16 f16x8 __attribute__((ext_vector_type(8)));
typedef float f32x4 __attribute__((ext_vector_type(4)));

__device__ inline unsigned short f2bf(float f) {  // fp32 -> bf16 RNE
  unsigned u = __float_as_uint(f);
  u += 0x7fffu + ((u >> 16) & 1u);
  return (unsigned short)(u >> 16);
}
__device__ inline float bf2f(unsigned short h) {
  return __uint_as_float(((unsigned)h) << 16);
}
__device__ inline unsigned short f2h(float f) {   // fp32 -> fp16 RNE (bits)
  union { _Float16 h; unsigned short u; } cv;
  cv.h = (_Float16)f;
  return cv.u;
}

// ================= fused prep: zero packed/psum/gcnt, feat->bf16, W->fp16^T ==

__global__ __launch_bounds__(256)
void k_prep(unsigned long long* __restrict__ packed, double* __restrict__ psum,
            float* __restrict__ gcnt,
            const float* __restrict__ feature, ushort* __restrict__ featb,
            const float* __restrict__ W1, ushort* __restrict__ w1h,
            const float* __restrict__ W2, ushort* __restrict__ w2h,
            const float* __restrict__ W3, ushort* __restrict__ w3h,
            int N, int BC, int Bn, int NF, int F, int D2, int D3,
            int nA, int nB, int nC) {
  int b = blockIdx.x;
  int t = threadIdx.x;
  if (b < nA) {
    int i = b * 256 + t;
    if (i < N) packed[i] = 0ull;
  } else if (b < nA + nB) {
    int i = (b - nA) * 256 + t;
    if (i < BC) psum[i] = 0.0;
    if (i < Bn) gcnt[i] = 0.f;
  } else if (b < nA + nB + nC) {
    int base = ((b - nA - nB) * 256 + t) * 4;
    if (base < NF) {
      float4 v = *reinterpret_cast<const float4*>(feature + base);
      ushort4 h;
      h.x = f2bf(v.x); h.y = f2bf(v.y); h.z = f2bf(v.z); h.w = f2bf(v.w);
      *reinterpret_cast<ushort4*>(featb + base) = h;
    }
  } else {
    int idx = (b - nA - nB - nC) * 256 + t;
    int s1 = F * F, s2 = s1 + F * D2, s3 = s2 + D2 * D3;
    if (idx < s1) {
      int k = idx / F, n = idx - k * F;
      w1h[(size_t)n * F + k] = f2h(W1[idx]);
    } else if (idx < s2) {
      int i2 = idx - s1; int k = i2 / D2, n = i2 - k * D2;
      w2h[(size_t)n * F + k] = f2h(W2[i2]);
    } else if (idx < s3) {
      int i3 = idx - s2; int k = i3 / D3, n = i3 - k * D3;
      w3h[(size_t)n * D2 + k] = f2h(W3[i3]);
    }
  }
}

// ================= degree/count: 4 edges per thread for atomic MLP =========
// packed[d]: high 24 bits = count, low 40 bits = sum(ew) in 2^-30 fixed pt.
// Returning atomic's old>>40 = edge's rank within its dst row.

__global__ __launch_bounds__(256)
void k_count_pack(const int* __restrict__ dst, const float* __restrict__ ew,
                  unsigned long long* __restrict__ packed,
                  int* __restrict__ rank, int E) {
  const int b0 = blockIdx.x * 1024 + threadIdx.x;
  int d[4]; float w[4]; unsigned long long old[4];
#pragma unroll
  for (int j = 0; j < 4; j++) {
    int e = b0 + 256 * j;
    if (e < E) { d[j] = dst[e]; w[j] = ew[e]; }
  }
#pragma unroll
  for (int j = 0; j < 4; j++) {
    int e = b0 + 256 * j;
    if (e < E) {
      unsigned long long q = (unsigned long long)(w[j] * 1073741824.0f + 0.5f);
      old[j] = atomicAdd(&packed[d[j]], (1ull << 40) | q);
    }
  }
#pragma unroll
  for (int j = 0; j < 4; j++) {
    int e = b0 + 256 * j;
    if (e < E) rank[e] = (int)(old[j] >> 40);
  }
}

// scan of counts + dinv/selfnorm (fused); 1024 elems / block
__global__ __launch_bounds__(256)
void k_scan1(const unsigned long long* __restrict__ packed, int* __restrict__ rs,
             int* __restrict__ bsum, float* __restrict__ dinv,
             float* __restrict__ sn, int N) {
  __shared__ int sh[256];
  const int t = threadIdx.x;
  const int base = blockIdx.x * 1024;
  int v[4]; int s = 0;
#pragma unroll
  for (int j = 0; j < 4; j++) {
    int idx = base + t * 4 + j;
    if (idx < N) {
      unsigned long long p = packed[idx];
      v[j] = (int)(p >> 40);
      double deg = 1.0 + (double)(p & 0xFFFFFFFFFFull) * (1.0 / 1073741824.0);
      float r = (float)(1.0 / sqrt(deg));
      dinv[idx] = r;
      sn[idx] = r * r;
    } else v[j] = 0;
    s += v[j];
  }
  sh[t] = s;
  __syncthreads();
  for (int off = 1; off < 256; off <<= 1) {
    int x = (t >= off) ? sh[t - off] : 0;
    __syncthreads();
    sh[t] += x;
    __syncthreads();
  }
  int run = sh[t] - s;
#pragma unroll
  for (int j = 0; j < 4; j++) {
    int idx = base + t * 4 + j;
    if (idx < N) rs[idx] = run;
    run += v[j];
  }
  if (t == 255) bsum[blockIdx.x] = sh[255];
}

// fused scan2+scan3: thread 0 computes block's chunk prefix (<=~100 iters)
__global__ __launch_bounds__(256)
void k_scan23(int* __restrict__ rs, const int* __restrict__ bsum, int N, int E) {
  __shared__ int spre;
  const int chunk = blockIdx.x >> 2;   // 4 blocks of 256 per 1024-chunk
  if (threadIdx.x == 0) {
    int pre = 0;
    for (int t = 0; t < chunk; t++) pre += bsum[t];
    spre = pre;
  }
  __syncthreads();
  int i = blockIdx.x * 256 + threadIdx.x;
  if (i < N) rs[i] += spre;
  if (i == 0) rs[N] = E;   // row-end sentinel
}

// no atomics: pos = rs[dst] + rank
__global__ void k_csr_fill(const int* __restrict__ src, const int* __restrict__ dst,
                           const float* __restrict__ ew, const float* __restrict__ dinv,
                           const int* __restrict__ rs, const int* __restrict__ rank,
                           int2* __restrict__ epack, int E) {
  int e = blockIdx.x * blockDim.x + threadIdx.x;
  if (e >= E) return;
  int d = dst[e], s = src[e];
  int pos = rs[d] + rank[e];
  float w = dinv[s] * ew[e] * dinv[d];
  epack[pos] = make_int2(s, __float_as_int(w));
}

// ================= CSR gather aggregation (bf16 in, fp16 out) ======

__device__ inline void bf8_fma(const int4 v, float w, float* acc) {
  acc[0] = fmaf(__uint_as_float((unsigned)v.x << 16), w, acc[0]);
  acc[1] = fmaf(__uint_as_float((unsigned)v.x & 0xffff0000u), w, acc[1]);
  acc[2] = fmaf(__uint_as_float((unsigned)v.y << 16), w, acc[2]);
  acc[3] = fmaf(__uint_as_float((unsigned)v.y & 0xffff0000u), w, acc[3]);
  acc[4] = fmaf(__uint_as_float((unsigned)v.z << 16), w, acc[4]);
  acc[5] = fmaf(__uint_as_float((unsigned)v.z & 0xffff0000u), w, acc[5]);
  acc[6] = fmaf(__uint_as_float((unsigned)v.w << 16), w, acc[6]);
  acc[7] = fmaf(__uint_as_float((unsigned)v.w & 0xffff0000u), w, acc[7]);
}

template<int LOG2L>
__global__ __launch_bounds__(256)
void k_aggregate_b(const ushort* __restrict__ Xb, const int* __restrict__ rs,
                   const int2* __restrict__ epack, const float* __restrict__ sn,
                   ushort* __restrict__ AH, int N) {
  const int t = blockIdx.x * blockDim.x + threadIdx.x;
  const int row = t >> LOG2L;
  if (row >= N) return;
  const int L = 1 << LOG2L;
  const int D = L << 3;
  const int c = (t & (L - 1)) << 3;

  float acc[8];
  {
    int4 v = *reinterpret_cast<const int4*>(Xb + (size_t)row * D + c);
    float s = sn[row];
    acc[0] = s * __uint_as_float((unsigned)v.x << 16);
    acc[1] = s * __uint_as_float((unsigned)v.x & 0xffff0000u);
    acc[2] = s * __uint_as_float((unsigned)v.y << 16);
    acc[3] = s * __uint_as_float((unsigned)v.y & 0xffff0000u);
    acc[4] = s * __uint_as_float((unsigned)v.z << 16);
    acc[5] = s * __uint_as_float((unsigned)v.z & 0xffff0000u);
    acc[6] = s * __uint_as_float((unsigned)v.w << 16);
    acc[7] = s * __uint_as_float((unsigned)v.w & 0xffff0000u);
  }
  const int p0 = rs[row], pe = rs[row + 1];
  int i = p0;
  if ((i & 1) && i < pe) {
    int2 e = epack[i];
    int4 v = *reinterpret_cast<const int4*>(Xb + (size_t)e.x * D + c);
    bf8_fma(v, __int_as_float(e.y), acc);
    i++;
  }
  for (; i + 2 <= pe; i += 2) {
    int4 e2 = *reinterpret_cast<const int4*>(&epack[i]);
    int4 v0 = *reinterpret_cast<const int4*>(Xb + (size_t)e2.x * D + c);
    int4 v1 = *reinterpret_cast<const int4*>(Xb + (size_t)e2.z * D + c);
    bf8_fma(v0, __int_as_float(e2.y), acc);
    bf8_fma(v1, __int_as_float(e2.w), acc);
  }
  if (i < pe) {
    int2 e = epack[i];
    int4 v = *reinterpret_cast<const int4*>(Xb + (size_t)e.x * D + c);
    bf8_fma(v, __int_as_float(e.y), acc);
  }
  ushort h[8];
#pragma unroll
  for (int j = 0; j < 8; j++) h[j] = f2h(acc[j]);
  size_t o = (size_t)row * D + c;
  *reinterpret_cast<ushort4*>(AH + o)     = make_ushort4(h[0], h[1], h[2], h[3]);
  *reinterpret_cast<ushort4*>(AH + o + 4) = make_ushort4(h[4], h[5], h[6], h[7]);
}

// ================= fp16 MFMA GEMM: Y = relu(A @ W + b), bf16 out ==========

template<int KT, int NT>
__global__ __launch_bounds__(256)
void k_gemm_mfma(const ushort* __restrict__ Ah, const ushort* __restrict__ Bh,
                 const float* __restrict__ bias, ushort* __restrict__ Y,
                 int N, int D) {
  constexpr int PK = 72;
  __shared__ __align__(16) ushort sAh[128 * PK];
  __shared__ __align__(16) ushort sBh[NT * PK];
  const int t = threadIdx.x;
  const int wave = t >> 6, lane = t & 63;
  const int quad = lane >> 4, l16 = lane & 15;
  const int m0 = blockIdx.y * 128;
  const int n0 = blockIdx.x * NT;

  f32x4 acc[2][NT / 16];
#pragma unroll
  for (int mi = 0; mi < 2; mi++)
#pragma unroll
    for (int ni = 0; ni < NT / 16; ni++) acc[mi][ni] = (f32x4){0.f, 0.f, 0.f, 0.f};

  for (int k0 = 0; k0 < KT; k0 += 64) {
    if (k0) __syncthreads();
#pragma unroll
    for (int it = 0; it < 4; it++) {
      int c = t + 256 * it;
      int row = c >> 3, kc = (c & 7) << 3;
      int gr = m0 + row; if (gr >= N) gr = N - 1;
      *reinterpret_cast<int4*>(&sAh[row * PK + kc]) =
          *reinterpret_cast<const int4*>(Ah + (size_t)gr * KT + k0 + kc);
    }
#pragma unroll
    for (int it = 0; it < NT / 32; it++) {
      int c = t + 256 * it;
      int row = c >> 3, kc = (c & 7) << 3;
      *reinterpret_cast<int4*>(&sBh[row * PK + kc]) =
          *reinterpret_cast<const int4*>(Bh + (size_t)(n0 + row) * KT + k0 + kc);
    }
    __syncthreads();
#pragma unroll
    for (int ks = 0; ks < 2; ks++) {
      const int kk = ks * 32 + quad * 8;
      f16x8 aH[2];
#pragma unroll
      for (int mi = 0; mi < 2; mi++) {
        int r = wave * 32 + mi * 16 + l16;
        aH[mi] = *reinterpret_cast<const f16x8*>(&sAh[r * PK + kk]);
      }
#pragma unroll
      for (int ni = 0; ni < NT / 16; ni++) {
        int r = ni * 16 + l16;
        f16x8 bH = *reinterpret_cast<const f16x8*>(&sBh[r * PK + kk]);
#pragma unroll
        for (int mi = 0; mi < 2; mi++)
          acc[mi][ni] = __builtin_amdgcn_mfma_f32_16x16x32_f16(aH[mi], bH, acc[mi][ni], 0, 0, 0);
      }
    }
  }
#pragma unroll
  for (int mi = 0; mi < 2; mi++) {
    int rb = m0 + wave * 32 + mi * 16 + quad * 4;
#pragma unroll
    for (int ni = 0; ni < NT / 16; ni++) {
      int col = n0 + ni * 16 + l16;
      float bv = bias[col];
#pragma unroll
      for (int r = 0; r < 4; r++) {
        int row = rb + r;
        if (row < N)
          Y[(size_t)row * D + col] = f2bf(fmaxf(acc[mi][ni][r] + bv, 0.f));
      }
    }
  }
}

// ================= pooling (sorted protein_batch) =================

__global__ void k_pool(const ushort* __restrict__ X3b, const float* __restrict__ feat,
                       const int* __restrict__ pb, double* __restrict__ psum,
                       int N, int D3, int F) {
  const int c = threadIdx.x;
  const int C = D3 + F;
  int i0 = blockIdx.x * 64;
  if (i0 >= N) return;
  int iend = i0 + 64; if (iend > N) iend = N;
  double acc = 0.0;
  int cur = pb[i0];
  for (int i = i0; i < iend; i++) {
    int b = pb[i];
    if (b != cur) {
      atomicAdd(&psum[(size_t)cur * C + c], acc);
      acc = 0.0; cur = b;
    }
    float v;
    if (c < D3) v = bf2f(X3b[(size_t)i * D3 + c]);
    else        v = feat[(size_t)i * F + (c - D3)];
    acc += (double)v;
  }
  atomicAdd(&psum[(size_t)cur * C + c], acc);
}

__global__ void k_count(const int* __restrict__ pb, float* __restrict__ cnt, int N) {
  int tchunk = blockIdx.x * blockDim.x + threadIdx.x;
  int i0 = tchunk * 64;
  if (i0 >= N) return;
  int iend = i0 + 64; if (iend > N) iend = N;
  float cacc = 0.f; int cur = pb[i0];
  for (int i = i0; i < iend; i++) {
    int b = pb[i];
    if (b != cur) { atomicAdd(&cnt[cur], cacc); cacc = 0.f; cur = b; }
    cacc += 1.f;
  }
  atomicAdd(&cnt[cur], cacc);
}

// ================= FC head (gc normalization fused into fc1) ==============

__global__ __launch_bounds__(256)
void k_fc1(const double* __restrict__ psum, const float* __restrict__ cnt,
           const float* __restrict__ Wf1, const float* __restrict__ bf1,
           float* __restrict__ hidden, int C, int Hh) {
  const int b = blockIdx.y;
  __shared__ float gcs[384];
  float invc = 1.f / fmaxf(cnt[b], 1.f);
  for (int c = threadIdx.x; c < C; c += 256)
    gcs[c] = (float)psum[(size_t)b * C + c] * invc;
  __syncthreads();
  const int j = blockIdx.x * 256 + threadIdx.x;
  if (j >= Hh) return;
  const float* w = Wf1 + j;
  float a0 = 0.f, a1 = 0.f, a2 = 0.f, a3 = 0.f;
  int c = 0;
  for (; c + 4 <= C; c += 4) {
    a0 = fmaf(gcs[c + 0], w[(size_t)(c + 0) * Hh], a0);
    a1 = fmaf(gcs[c + 1], w[(size_t)(c + 1) * Hh], a1);
    a2 = fmaf(gcs[c + 2], w[(size_t)(c + 2) * Hh], a2);
    a3 = fmaf(gcs[c + 3], w[(size_t)(c + 3) * Hh], a3);
  }
  for (; c < C; c++) a0 = fmaf(gcs[c], w[(size_t)c * Hh], a0);
  float r = ((a0 + a1) + (a2 + a3)) + bf1[j];
  hidden[(size_t)b * Hh + j] = fmaxf(r, 0.f);
}

__global__ void k_fc2(const float* __restrict__ hidden, const float* __restrict__ Wf2,
                      const float* __restrict__ bf2, float* __restrict__ out, int Hh) {
  int b = blockIdx.x;
  int lane = threadIdx.x;  // 64
  double s = 0.0;
  for (int j = lane; j < Hh; j += 64) s += (double)hidden[(size_t)b * Hh + j] * (double)Wf2[j];
#pragma unroll
  for (int off = 32; off > 0; off >>= 1) s += __shfl_down(s, off);
  if (lane == 0) out[b] = (float)s + bf2[0];
}

// ================= launch =================

extern "C" void kernel_launch(void* const* d_in, const int* in_sizes, int n_in,
                              void* d_out, int out_size, void* d_ws, size_t ws_size,
                              hipStream_t stream) {
  const float* feature = (const float*)d_in[0];
  const int*   eidx    = (const int*)  d_in[1];
  const float* weight  = (const float*)d_in[2];
  const int*   pb      = (const int*)  d_in[3];
  const float* W1  = (const float*)d_in[4];
  const float* b1  = (const float*)d_in[5];
  const float* W2  = (const float*)d_in[6];
  const float* b2  = (const float*)d_in[7];
  const float* W3  = (const float*)d_in[8];
  const float* b3  = (const float*)d_in[9];
  const float* Wf1 = (const float*)d_in[10];
  const float* bf1 = (const float*)d_in[11];
  const float* Wf2 = (const float*)d_in[12];
  const float* bf2 = (const float*)d_in[13];

  const int F  = in_sizes[5];          // 64
  const int D2 = in_sizes[7];          // 128
  const int D3 = in_sizes[9];          // 256
  const int Hh = in_sizes[11];         // 1024
  const int N  = in_sizes[0] / F;      // 100000
  const int E  = in_sizes[1] / 2;      // 1200000
  const int B  = out_size;             // 256
  const int C  = D3 + F;               // 320

  const int* srcp = eidx;
  const int* dstp = eidx + E;
  const int nscan = (N + 1023) / 1024;

  auto al = [](size_t x) { return (x + 255) & ~(size_t)255; };
  size_t off = 0;
  auto alloc = [&](size_t bytes) { size_t o = off; off += al(bytes); return o; };
  size_t o_pack  = alloc((size_t)N * 8);
  size_t o_dinv  = alloc((size_t)N * 4);
  size_t o_sn    = alloc((size_t)N * 4);
  size_t o_rs    = alloc((size_t)(N + 1) * 4);
  size_t o_rank  = alloc((size_t)E * 4);
  size_t o_bsum  = alloc((size_t)nscan * 4);
  size_t o_epack = alloc((size_t)E * 8);
  size_t o_featb = alloc((size_t)N * F  * 2);
  size_t o_x1b   = alloc((size_t)N * F  * 2);
  size_t o_x2b   = alloc((size_t)N * D2 * 2);
  size_t o_x3b   = alloc((size_t)N * D3 * 2);
  size_t o_aggh  = alloc((size_t)N * D2 * 2);   // fp16 (max K = 128)
  size_t o_w1h   = alloc((size_t)F  * F  * 2);
  size_t o_w2h   = alloc((size_t)F  * D2 * 2);
  size_t o_w3h   = alloc((size_t)D2 * D3 * 2);
  size_t o_psum  = alloc((size_t)B * C * 8);
  size_t o_gcnt  = alloc((size_t)B * 4);
  size_t o_hid   = alloc((size_t)B * Hh * 4);
  if (off > ws_size) {
    fprintf(stderr, "kernel_launch: workspace too small: need %zu, have %zu\n", off, ws_size);
    return;
  }

  char* ws = (char*)d_ws;
  unsigned long long* packed = (unsigned long long*)(ws + o_pack);
  float*  dinv  = (float*)(ws + o_dinv);
  float*  sn    = (float*)(ws + o_sn);
  int*    rs    = (int*)  (ws + o_rs);
  int*    rank  = (int*)  (ws + o_rank);
  int*    bsum  = (int*)  (ws + o_bsum);
  int2*   epack = (int2*) (ws + o_epack);
  ushort* featb = (ushort*)(ws + o_featb);
  ushort* x1b   = (ushort*)(ws + o_x1b);
  ushort* x2b   = (ushort*)(ws + o_x2b);
  ushort* x3b   = (ushort*)(ws + o_x3b);
  ushort* aggh  = (ushort*)(ws + o_aggh);
  ushort* w1h   = (ushort*)(ws + o_w1h);
  ushort* w2h   = (ushort*)(ws + o_w2h);
  ushort* w3h   = (ushort*)(ws + o_w3h);
  double* psum  = (double*)(ws + o_psum);
  float*  gcnt  = (float*)(ws + o_gcnt);
  float*  hid   = (float*)(ws + o_hid);
  float*  out   = (float*)d_out;

  // ---- fused prep ----
  const int BC = B * C, NF = N * F;
  const int nA = (N + 255) / 256;
  const int nB = (BC + 255) / 256;
  const int nC = (NF / 4 + 255) / 256;
  const int nD = (F * F + F * D2 + D2 * D3 + 255) / 256;
  k_prep<<<nA + nB + nC + nD, 256, 0, stream>>>(
      packed, psum, gcnt, feature, featb, W1, w1h, W2, w2h, W3, w3h,
      N, BC, B, NF, F, D2, D3, nA, nB, nC);

  // ---- CSR build ----
  k_count_pack<<<(E + 1023) / 1024, 256, 0, stream>>>(dstp, weight, packed, rank, E);
  k_scan1     <<<nscan, 256, 0, stream>>>(packed, rs, bsum, dinv, sn, N);
  k_scan23    <<<(N + 255) / 256, 256, 0, stream>>>(rs, bsum, N, E);
  k_csr_fill  <<<(E + 255) / 256, 256, 0, stream>>>(srcp, dstp, weight, dinv, rs, rank, epack, E);

  const int gy = (N + 127) / 128;

  // ---- layer 1: agg(featb)[N,64] @ W1[64,64] -> x1b (bf16) ----
  {
    int tot = N * (F / 8);
    k_aggregate_b<3><<<(tot + 255) / 256, 256, 0, stream>>>(featb, rs, epack, sn, aggh, N);
    dim3 g(1, gy);
    k_gemm_mfma<64, 64><<<g, 256, 0, stream>>>(aggh, w1h, b1, x1b, N, F);
  }
  // ---- layer 2: agg(x1b)[N,64] @ W2[64,128] -> x2b (bf16) ----
  {
    int tot = N * (F / 8);
    k_aggregate_b<3><<<(tot + 255) / 256, 256, 0, stream>>>(x1b, rs, epack, sn, aggh, N);
    dim3 g(1, gy);
    k_gemm_mfma<64, 128><<<g, 256, 0, stream>>>(aggh, w2h, b2, x2b, N, D2);
  }
  // ---- layer 3: agg(x2b)[N,128] @ W3[128,256] -> x3b (bf16) ----
  {
    int tot = N * (D2 / 8);
    k_aggregate_b<4><<<(tot + 255) / 256, 256, 0, stream>>>(x2b, rs, epack, sn, aggh, N);
    dim3 g(2, gy);
    k_gemm_mfma<128, 128><<<g, 256, 0, stream>>>(aggh, w3h, b3, x3b, N, D3);
  }

  // ---- pooling + head ----
  k_count<<<((N + 63) / 64 + 255) / 256, 256, 0, stream>>>(pb, gcnt, N);
  k_pool <<<(N + 63) / 64, C, 0, stream>>>(x3b, feature, pb, psum, N, D3, F);
  {
    dim3 g((Hh + 255) / 256, B);
    k_fc1<<<g, 256, 0, stream>>>(psum, gcnt, Wf1, bf1, hid, C, Hh);
  }
  k_fc2  <<<B, 64, 0, stream>>>(hid, Wf2, bf2, out, Hh);
}

// Round 11
// 441.982 us; speedup vs baseline: 1.2017x; 1.0360x over previous
//
#include <hip/hip_runtime.h>
#include <cstdio>
#include <cstdint>

typedef _Float16 f16x8 __attribute__((ext_vector_type(8)));
typedef float f32x4 __attribute__((ext_vector_type(4)));

__device__ inline unsigned short f2bf(float f) {  // fp32 -> bf16 RNE
  unsigned u = __float_as_uint(f);
  u += 0x7fffu + ((u >> 16) & 1u);
  return (unsigned short)(u >> 16);
}
__device__ inline float bf2f(unsigned short h) {
  return __uint_as_float(((unsigned)h) << 16);
}
__device__ inline unsigned short f2h(float f) {   // fp32 -> fp16 RNE (bits)
  union { _Float16 h; unsigned short u; } cv;
  cv.h = (_Float16)f;
  return cv.u;
}

// ================= fused prep: zero psum/gcnt, feat->bf16, W->fp16^T ======

__global__ __launch_bounds__(256)
void k_prep(double* __restrict__ psum, float* __restrict__ gcnt,
            const float* __restrict__ feature, ushort* __restrict__ featb,
            const float* __restrict__ W1, ushort* __restrict__ w1h,
            const float* __restrict__ W2, ushort* __restrict__ w2h,
            const float* __restrict__ W3, ushort* __restrict__ w3h,
            int BC, int Bn, int NF, int F, int D2, int D3,
            int nB, int nC) {
  int b = blockIdx.x;
  int t = threadIdx.x;
  if (b < nB) {
    int i = b * 256 + t;
    if (i < BC) psum[i] = 0.0;
    if (i < Bn) gcnt[i] = 0.f;
  } else if (b < nB + nC) {
    int base = ((b - nB) * 256 + t) * 4;
    if (base < NF) {
      float4 v = *reinterpret_cast<const float4*>(feature + base);
      ushort4 h;
      h.x = f2bf(v.x); h.y = f2bf(v.y); h.z = f2bf(v.z); h.w = f2bf(v.w);
      *reinterpret_cast<ushort4*>(featb + base) = h;
    }
  } else {
    int idx = (b - nB - nC) * 256 + t;
    int s1 = F * F, s2 = s1 + F * D2, s3 = s2 + D2 * D3;
    if (idx < s1) {
      int k = idx / F, n = idx - k * F;
      w1h[(size_t)n * F + k] = f2h(W1[idx]);
    } else if (idx < s2) {
      int i2 = idx - s1; int k = i2 / D2, n = i2 - k * D2;
      w2h[(size_t)n * F + k] = f2h(W2[i2]);
    } else if (idx < s3) {
      int i3 = idx - s2; int k = i3 / D3, n = i3 - k * D3;
      w3h[(size_t)n * D2 + k] = f2h(W3[i3]);
    }
  }
}

// ================= sort-based CSR build (ZERO global atomics) =============
// R8/R10 showed device-scope RMW rate ~21G/s is a hard floor; replace the
// 1.2M-atomic histogram with bucket sort by dst>>8 (256 nodes/bucket):
// bhist (LDS hist, plain writes) -> scan -> bscatter (LDS local rank) ->
// bproc (per-bucket LDS count/deg + rank2) -> scan -> csr_fill2.

__global__ __launch_bounds__(256)
void k_bhist(const int* __restrict__ dst, int* __restrict__ H,
             int NB, int E) {
  __shared__ int hist[512];
  const int t = threadIdx.x;
  for (int i = t; i < NB; i += 256) hist[i] = 0;
  __syncthreads();
  const int base = blockIdx.x * 1024 + t;
#pragma unroll
  for (int j = 0; j < 4; j++) {
    int e = base + 256 * j;
    if (e < E) atomicAdd(&hist[dst[e] >> 8], 1);
  }
  __syncthreads();
  for (int i = t; i < NB; i += 256) H[(size_t)blockIdx.x * NB + i] = hist[i];
}

// exclusive scan over T = NB*NBLK elems in bin-major order j=bin*NBLK+bi,
// reading block-major H[bi*NB+bin]; output S[j] (bin-major).
__global__ __launch_bounds__(256)
void k_bscan1(const int* __restrict__ H, int* __restrict__ S,
              int* __restrict__ bsum, int NB, int NBLK, int T) {
  __shared__ int sh[256];
  const int t = threadIdx.x;
  const int base = blockIdx.x * 1024;
  int v[4]; int s = 0;
#pragma unroll
  for (int j = 0; j < 4; j++) {
    int idx = base + t * 4 + j;
    if (idx < T) {
      int bin = idx / NBLK, bi = idx - bin * NBLK;
      v[j] = H[(size_t)bi * NB + bin];
    } else v[j] = 0;
    s += v[j];
  }
  sh[t] = s;
  __syncthreads();
  for (int off = 1; off < 256; off <<= 1) {
    int x = (t >= off) ? sh[t - off] : 0;
    __syncthreads();
    sh[t] += x;
    __syncthreads();
  }
  int run = sh[t] - s;
#pragma unroll
  for (int j = 0; j < 4; j++) {
    int idx = base + t * 4 + j;
    if (idx < T) S[idx] = run;
    run += v[j];
  }
  if (t == 255) bsum[blockIdx.x] = sh[255];
}

__global__ __launch_bounds__(256)
void k_bscan23(int* __restrict__ S, const int* __restrict__ bsum, int T) {
  __shared__ int spre;
  const int chunk = blockIdx.x >> 2;
  if (threadIdx.x == 0) {
    int pre = 0;
    for (int t = 0; t < chunk; t++) pre += bsum[t];
    spre = pre;
  }
  __syncthreads();
  int i = blockIdx.x * 256 + threadIdx.x;
  if (i < T) S[i] += spre;
}

// scatter edges into bucket-sorted order (stable-enough; any within-row
// permutation is valid — fp32 sum-order noise << threshold)
__global__ __launch_bounds__(256)
void k_bscatter(const int* __restrict__ src, const int* __restrict__ dst,
                const float* __restrict__ ew, const int* __restrict__ S,
                int* __restrict__ sdst, int2* __restrict__ ssw,
                int NB, int NBLK, int E) {
  __shared__ int cnt[512];
  __shared__ int sbase[512];
  const int t = threadIdx.x, bi = blockIdx.x;
  for (int i = t; i < NB; i += 256) {
    cnt[i] = 0;
    sbase[i] = S[(size_t)i * NBLK + bi];
  }
  __syncthreads();
  const int base = bi * 1024 + t;
#pragma unroll
  for (int j = 0; j < 4; j++) {
    int e = base + 256 * j;
    if (e < E) {
      int d = dst[e];
      int bin = d >> 8;
      int r = atomicAdd(&cnt[bin], 1);
      int pos = sbase[bin] + r;
      sdst[pos] = d;
      ssw[pos] = make_int2(src[e], __float_as_int(ew[e]));
    }
  }
}

// per-bucket: node counts (LDS returning atomic -> rank2), fp32 weighted
// degree (reference itself sums deg in fp32), coalesced cntN/wsumN write.
__global__ __launch_bounds__(256)
void k_bproc(const int* __restrict__ sdst, const int2* __restrict__ ssw,
             const int* __restrict__ S, int* __restrict__ rank2,
             int* __restrict__ cntN, float* __restrict__ wsumN,
             int NB, int NBLK, int N, int E) {
  __shared__ int cnt[256];
  __shared__ float wsm[256];
  const int t = threadIdx.x, bin = blockIdx.x;
  cnt[t] = 0; wsm[t] = 0.f;
  __syncthreads();
  const int start = S[(size_t)bin * NBLK];
  const int end = (bin + 1 < NB) ? S[(size_t)(bin + 1) * NBLK] : E;
  for (int p = start + t; p < end; p += 256) {
    int ld = sdst[p] & 255;
    rank2[p] = atomicAdd(&cnt[ld], 1);
    atomicAdd(&wsm[ld], __int_as_float(ssw[p].y));
  }
  __syncthreads();
  int n = bin * 256 + t;
  if (n < N) { cntN[n] = cnt[t]; wsumN[n] = wsm[t]; }
}

// scan of cntN -> rs; dinv/selfnorm fused (deg = 1 + wsum)
__global__ __launch_bounds__(256)
void k_scan1(const int* __restrict__ cntN, const float* __restrict__ wsumN,
             int* __restrict__ rs, int* __restrict__ bsum,
             float* __restrict__ dinv, float* __restrict__ sn, int N) {
  __shared__ int sh[256];
  const int t = threadIdx.x;
  const int base = blockIdx.x * 1024;
  int v[4]; int s = 0;
#pragma unroll
  for (int j = 0; j < 4; j++) {
    int idx = base + t * 4 + j;
    if (idx < N) {
      v[j] = cntN[idx];
      double deg = 1.0 + (double)wsumN[idx];
      float r = (float)(1.0 / sqrt(deg));
      dinv[idx] = r;
      sn[idx] = r * r;
    } else v[j] = 0;
    s += v[j];
  }
  sh[t] = s;
  __syncthreads();
  for (int off = 1; off < 256; off <<= 1) {
    int x = (t >= off) ? sh[t - off] : 0;
    __syncthreads();
    sh[t] += x;
    __syncthreads();
  }
  int run = sh[t] - s;
#pragma unroll
  for (int j = 0; j < 4; j++) {
    int idx = base + t * 4 + j;
    if (idx < N) rs[idx] = run;
    run += v[j];
  }
  if (t == 255) bsum[blockIdx.x] = sh[255];
}

__global__ __launch_bounds__(256)
void k_scan23(int* __restrict__ rs, const int* __restrict__ bsum, int N, int E) {
  __shared__ int spre;
  const int chunk = blockIdx.x >> 2;
  if (threadIdx.x == 0) {
    int pre = 0;
    for (int t = 0; t < chunk; t++) pre += bsum[t];
    spre = pre;
  }
  __syncthreads();
  int i = blockIdx.x * 256 + threadIdx.x;
  if (i < N) rs[i] += spre;
  if (i == 0) rs[N] = E;   // row-end sentinel
}

// final fill from bucket-sorted edges: epack scatter confined to ~24KB/bucket
__global__ void k_csr_fill2(const int* __restrict__ sdst, const int2* __restrict__ ssw,
                            const int* __restrict__ rank2, const int* __restrict__ rs,
                            const float* __restrict__ dinv,
                            int2* __restrict__ epack, int E) {
  int p = blockIdx.x * blockDim.x + threadIdx.x;
  if (p >= E) return;
  int d = sdst[p];
  int2 sw = ssw[p];
  float w = dinv[sw.x] * __int_as_float(sw.y) * dinv[d];
  epack[rs[d] + rank2[p]] = make_int2(sw.x, __float_as_int(w));
}

// ================= CSR gather aggregation (bf16 in, fp16 out) ======

__device__ inline void bf8_fma(const int4 v, float w, float* acc) {
  acc[0] = fmaf(__uint_as_float((unsigned)v.x << 16), w, acc[0]);
  acc[1] = fmaf(__uint_as_float((unsigned)v.x & 0xffff0000u), w, acc[1]);
  acc[2] = fmaf(__uint_as_float((unsigned)v.y << 16), w, acc[2]);
  acc[3] = fmaf(__uint_as_float((unsigned)v.y & 0xffff0000u), w, acc[3]);
  acc[4] = fmaf(__uint_as_float((unsigned)v.z << 16), w, acc[4]);
  acc[5] = fmaf(__uint_as_float((unsigned)v.z & 0xffff0000u), w, acc[5]);
  acc[6] = fmaf(__uint_as_float((unsigned)v.w << 16), w, acc[6]);
  acc[7] = fmaf(__uint_as_float((unsigned)v.w & 0xffff0000u), w, acc[7]);
}

template<int LOG2L>
__global__ __launch_bounds__(256)
void k_aggregate_b(const ushort* __restrict__ Xb, const int* __restrict__ rs,
                   const int2* __restrict__ epack, const float* __restrict__ sn,
                   ushort* __restrict__ AH, int N) {
  const int t = blockIdx.x * blockDim.x + threadIdx.x;
  const int row = t >> LOG2L;
  if (row >= N) return;
  const int L = 1 << LOG2L;
  const int D = L << 3;
  const int c = (t & (L - 1)) << 3;

  float acc[8];
  {
    int4 v = *reinterpret_cast<const int4*>(Xb + (size_t)row * D + c);
    float s = sn[row];
    acc[0] = s * __uint_as_float((unsigned)v.x << 16);
    acc[1] = s * __uint_as_float((unsigned)v.x & 0xffff0000u);
    acc[2] = s * __uint_as_float((unsigned)v.y << 16);
    acc[3] = s * __uint_as_float((unsigned)v.y & 0xffff0000u);
    acc[4] = s * __uint_as_float((unsigned)v.z << 16);
    acc[5] = s * __uint_as_float((unsigned)v.z & 0xffff0000u);
    acc[6] = s * __uint_as_float((unsigned)v.w << 16);
    acc[7] = s * __uint_as_float((unsigned)v.w & 0xffff0000u);
  }
  const int p0 = rs[row], pe = rs[row + 1];
  int i = p0;
  if ((i & 1) && i < pe) {
    int2 e = epack[i];
    int4 v = *reinterpret_cast<const int4*>(Xb + (size_t)e.x * D + c);
    bf8_fma(v, __int_as_float(e.y), acc);
    i++;
  }
  for (; i + 2 <= pe; i += 2) {
    int4 e2 = *reinterpret_cast<const int4*>(&epack[i]);
    int4 v0 = *reinterpret_cast<const int4*>(Xb + (size_t)e2.x * D + c);
    int4 v1 = *reinterpret_cast<const int4*>(Xb + (size_t)e2.z * D + c);
    bf8_fma(v0, __int_as_float(e2.y), acc);
    bf8_fma(v1, __int_as_float(e2.w), acc);
  }
  if (i < pe) {
    int2 e = epack[i];
    int4 v = *reinterpret_cast<const int4*>(Xb + (size_t)e.x * D + c);
    bf8_fma(v, __int_as_float(e.y), acc);
  }
  ushort h[8];
#pragma unroll
  for (int j = 0; j < 8; j++) h[j] = f2h(acc[j]);
  size_t o = (size_t)row * D + c;
  *reinterpret_cast<ushort4*>(AH + o)     = make_ushort4(h[0], h[1], h[2], h[3]);
  *reinterpret_cast<ushort4*>(AH + o + 4) = make_ushort4(h[4], h[5], h[6], h[7]);
}

// ================= fp16 MFMA GEMM: Y = relu(A @ W + b), bf16 out ==========

template<int KT, int NT>
__global__ __launch_bounds__(256)
void k_gemm_mfma(const ushort* __restrict__ Ah, const ushort* __restrict__ Bh,
                 const float* __restrict__ bias, ushort* __restrict__ Y,
                 int N, int D) {
  constexpr int PK = 72;
  __shared__ __align__(16) ushort sAh[128 * PK];
  __shared__ __align__(16) ushort sBh[NT * PK];
  const int t = threadIdx.x;
  const int wave = t >> 6, lane = t & 63;
  const int quad = lane >> 4, l16 = lane & 15;
  const int m0 = blockIdx.y * 128;
  const int n0 = blockIdx.x * NT;

  f32x4 acc[2][NT / 16];
#pragma unroll
  for (int mi = 0; mi < 2; mi++)
#pragma unroll
    for (int ni = 0; ni < NT / 16; ni++) acc[mi][ni] = (f32x4){0.f, 0.f, 0.f, 0.f};

  for (int k0 = 0; k0 < KT; k0 += 64) {
    if (k0) __syncthreads();
#pragma unroll
    for (int it = 0; it < 4; it++) {
      int c = t + 256 * it;
      int row = c >> 3, kc = (c & 7) << 3;
      int gr = m0 + row; if (gr >= N) gr = N - 1;
      *reinterpret_cast<int4*>(&sAh[row * PK + kc]) =
          *reinterpret_cast<const int4*>(Ah + (size_t)gr * KT + k0 + kc);
    }
#pragma unroll
    for (int it = 0; it < NT / 32; it++) {
      int c = t + 256 * it;
      int row = c >> 3, kc = (c & 7) << 3;
      *reinterpret_cast<int4*>(&sBh[row * PK + kc]) =
          *reinterpret_cast<const int4*>(Bh + (size_t)(n0 + row) * KT + k0 + kc);
    }
    __syncthreads();
#pragma unroll
    for (int ks = 0; ks < 2; ks++) {
      const int kk = ks * 32 + quad * 8;
      f16x8 aH[2];
#pragma unroll
      for (int mi = 0; mi < 2; mi++) {
        int r = wave * 32 + mi * 16 + l16;
        aH[mi] = *reinterpret_cast<const f16x8*>(&sAh[r * PK + kk]);
      }
#pragma unroll
      for (int ni = 0; ni < NT / 16; ni++) {
        int r = ni * 16 + l16;
        f16x8 bH = *reinterpret_cast<const f16x8*>(&sBh[r * PK + kk]);
#pragma unroll
        for (int mi = 0; mi < 2; mi++)
          acc[mi][ni] = __builtin_amdgcn_mfma_f32_16x16x32_f16(aH[mi], bH, acc[mi][ni], 0, 0, 0);
      }
    }
  }
#pragma unroll
  for (int mi = 0; mi < 2; mi++) {
    int rb = m0 + wave * 32 + mi * 16 + quad * 4;
#pragma unroll
    for (int ni = 0; ni < NT / 16; ni++) {
      int col = n0 + ni * 16 + l16;
      float bv = bias[col];
#pragma unroll
      for (int r = 0; r < 4; r++) {
        int row = rb + r;
        if (row < N)
          Y[(size_t)row * D + col] = f2bf(fmaxf(acc[mi][ni][r] + bv, 0.f));
      }
    }
  }
}

// ================= pooling (sorted protein_batch; count fused c==0) =======

__global__ void k_pool(const ushort* __restrict__ X3b, const float* __restrict__ feat,
                       const int* __restrict__ pb, double* __restrict__ psum,
                       float* __restrict__ gcnt, int N, int D3, int F) {
  const int c = threadIdx.x;
  const int C = D3 + F;
  int i0 = blockIdx.x * 64;
  if (i0 >= N) return;
  int iend = i0 + 64; if (iend > N) iend = N;
  double acc = 0.0;
  float cacc = 0.f;
  int cur = pb[i0];
  for (int i = i0; i < iend; i++) {
    int b = pb[i];
    if (b != cur) {
      atomicAdd(&psum[(size_t)cur * C + c], acc);
      if (c == 0) atomicAdd(&gcnt[cur], cacc);
      acc = 0.0; cacc = 0.f; cur = b;
    }
    float v;
    if (c < D3) v = bf2f(X3b[(size_t)i * D3 + c]);
    else        v = feat[(size_t)i * F + (c - D3)];
    acc += (double)v;
    cacc += 1.f;
  }
  atomicAdd(&psum[(size_t)cur * C + c], acc);
  if (c == 0) atomicAdd(&gcnt[cur], cacc);
}

// ================= FC head (gc normalization fused into fc1) ==============

__global__ __launch_bounds__(256)
void k_fc1(const double* __restrict__ psum, const float* __restrict__ cnt,
           const float* __restrict__ Wf1, const float* __restrict__ bf1,
           float* __restrict__ hidden, int C, int Hh) {
  const int b = blockIdx.y;
  __shared__ float gcs[384];
  float invc = 1.f / fmaxf(cnt[b], 1.f);
  for (int c = threadIdx.x; c < C; c += 256)
    gcs[c] = (float)psum[(size_t)b * C + c] * invc;
  __syncthreads();
  const int j = blockIdx.x * 256 + threadIdx.x;
  if (j >= Hh) return;
  const float* w = Wf1 + j;
  float a0 = 0.f, a1 = 0.f, a2 = 0.f, a3 = 0.f;
  int c = 0;
  for (; c + 4 <= C; c += 4) {
    a0 = fmaf(gcs[c + 0], w[(size_t)(c + 0) * Hh], a0);
    a1 = fmaf(gcs[c + 1], w[(size_t)(c + 1) * Hh], a1);
    a2 = fmaf(gcs[c + 2], w[(size_t)(c + 2) * Hh], a2);
    a3 = fmaf(gcs[c + 3], w[(size_t)(c + 3) * Hh], a3);
  }
  for (; c < C; c++) a0 = fmaf(gcs[c], w[(size_t)c * Hh], a0);
  float r = ((a0 + a1) + (a2 + a3)) + bf1[j];
  hidden[(size_t)b * Hh + j] = fmaxf(r, 0.f);
}

__global__ void k_fc2(const float* __restrict__ hidden, const float* __restrict__ Wf2,
                      const float* __restrict__ bf2, float* __restrict__ out, int Hh) {
  int b = blockIdx.x;
  int lane = threadIdx.x;  // 64
  double s = 0.0;
  for (int j = lane; j < Hh; j += 64) s += (double)hidden[(size_t)b * Hh + j] * (double)Wf2[j];
#pragma unroll
  for (int off = 32; off > 0; off >>= 1) s += __shfl_down(s, off);
  if (lane == 0) out[b] = (float)s + bf2[0];
}

// ================= launch =================

extern "C" void kernel_launch(void* const* d_in, const int* in_sizes, int n_in,
                              void* d_out, int out_size, void* d_ws, size_t ws_size,
                              hipStream_t stream) {
  const float* feature = (const float*)d_in[0];
  const int*   eidx    = (const int*)  d_in[1];
  const float* weight  = (const float*)d_in[2];
  const int*   pb      = (const int*)  d_in[3];
  const float* W1  = (const float*)d_in[4];
  const float* b1  = (const float*)d_in[5];
  const float* W2  = (const float*)d_in[6];
  const float* b2  = (const float*)d_in[7];
  const float* W3  = (const float*)d_in[8];
  const float* b3  = (const float*)d_in[9];
  const float* Wf1 = (const float*)d_in[10];
  const float* bf1 = (const float*)d_in[11];
  const float* Wf2 = (const float*)d_in[12];
  const float* bf2 = (const float*)d_in[13];

  const int F  = in_sizes[5];          // 64
  const int D2 = in_sizes[7];          // 128
  const int D3 = in_sizes[9];          // 256
  const int Hh = in_sizes[11];         // 1024
  const int N  = in_sizes[0] / F;      // 100000
  const int E  = in_sizes[1] / 2;      // 1200000
  const int B  = out_size;             // 256
  const int C  = D3 + F;               // 320

  const int* srcp = eidx;
  const int* dstp = eidx + E;

  const int NB   = (N + 255) / 256;      // buckets (<=512)
  const int NBLK = (E + 1023) / 1024;    // edge blocks
  const int T    = NB * NBLK;            // scan length
  const int nscanb = (T + 1023) / 1024;
  const int nscan  = (N + 1023) / 1024;

  auto al = [](size_t x) { return (x + 255) & ~(size_t)255; };
  size_t off = 0;
  auto alloc = [&](size_t bytes) { size_t o = off; off += al(bytes); return o; };
  size_t o_H     = alloc((size_t)T * 4);
  size_t o_S     = alloc((size_t)T * 4);
  size_t o_bsb   = alloc((size_t)nscanb * 4);
  size_t o_sdst  = alloc((size_t)E * 4);
  size_t o_ssw   = alloc((size_t)E * 8);
  size_t o_rank2 = alloc((size_t)E * 4);
  size_t o_cntN  = alloc((size_t)N * 4);
  size_t o_wsumN = alloc((size_t)N * 4);
  size_t o_dinv  = alloc((size_t)N * 4);
  size_t o_sn    = alloc((size_t)N * 4);
  size_t o_rs    = alloc((size_t)(N + 1) * 4);
  size_t o_bsum  = alloc((size_t)nscan * 4);
  size_t o_epack = alloc((size_t)E * 8);
  size_t o_featb = alloc((size_t)N * F  * 2);
  size_t o_x1b   = alloc((size_t)N * F  * 2);
  size_t o_x2b   = alloc((size_t)N * D2 * 2);
  size_t o_x3b   = alloc((size_t)N * D3 * 2);
  size_t o_aggh  = alloc((size_t)N * D2 * 2);   // fp16 (max K = 128)
  size_t o_w1h   = alloc((size_t)F  * F  * 2);
  size_t o_w2h   = alloc((size_t)F  * D2 * 2);
  size_t o_w3h   = alloc((size_t)D2 * D3 * 2);
  size_t o_psum  = alloc((size_t)B * C * 8);
  size_t o_gcnt  = alloc((size_t)B * 4);
  size_t o_hid   = alloc((size_t)B * Hh * 4);
  if (off > ws_size) {
    fprintf(stderr, "kernel_launch: workspace too small: need %zu, have %zu\n", off, ws_size);
    return;
  }

  char* ws = (char*)d_ws;
  int*    H     = (int*)  (ws + o_H);
  int*    S     = (int*)  (ws + o_S);
  int*    bsb   = (int*)  (ws + o_bsb);
  int*    sdst  = (int*)  (ws + o_sdst);
  int2*   ssw   = (int2*) (ws + o_ssw);
  int*    rank2 = (int*)  (ws + o_rank2);
  int*    cntN  = (int*)  (ws + o_cntN);
  float*  wsumN = (float*)(ws + o_wsumN);
  float*  dinv  = (float*)(ws + o_dinv);
  float*  sn    = (float*)(ws + o_sn);
  int*    rs    = (int*)  (ws + o_rs);
  int*    bsum  = (int*)  (ws + o_bsum);
  int2*   epack = (int2*) (ws + o_epack);
  ushort* featb = (ushort*)(ws + o_featb);
  ushort* x1b   = (ushort*)(ws + o_x1b);
  ushort* x2b   = (ushort*)(ws + o_x2b);
  ushort* x3b   = (ushort*)(ws + o_x3b);
  ushort* aggh  = (ushort*)(ws + o_aggh);
  ushort* w1h   = (ushort*)(ws + o_w1h);
  ushort* w2h   = (ushort*)(ws + o_w2h);
  ushort* w3h   = (ushort*)(ws + o_w3h);
  double* psum  = (double*)(ws + o_psum);
  float*  gcnt  = (float*)(ws + o_gcnt);
  float*  hid   = (float*)(ws + o_hid);
  float*  out   = (float*)d_out;

  // ---- fused prep ----
  const int BC = B * C, NF = N * F;
  const int nB = (BC + 255) / 256;
  const int nC = (NF / 4 + 255) / 256;
  const int nD = (F * F + F * D2 + D2 * D3 + 255) / 256;
  k_prep<<<nB + nC + nD, 256, 0, stream>>>(
      psum, gcnt, feature, featb, W1, w1h, W2, w2h, W3, w3h,
      BC, B, NF, F, D2, D3, nB, nC);

  // ---- sort-based CSR build (zero global atomics) ----
  k_bhist   <<<NBLK, 256, 0, stream>>>(dstp, H, NB, E);
  k_bscan1  <<<nscanb, 256, 0, stream>>>(H, S, bsb, NB, NBLK, T);
  k_bscan23 <<<(T + 255) / 256, 256, 0, stream>>>(S, bsb, T);
  k_bscatter<<<NBLK, 256, 0, stream>>>(srcp, dstp, weight, S, sdst, ssw, NB, NBLK, E);
  k_bproc   <<<NB, 256, 0, stream>>>(sdst, ssw, S, rank2, cntN, wsumN, NB, NBLK, N, E);
  k_scan1   <<<nscan, 256, 0, stream>>>(cntN, wsumN, rs, bsum, dinv, sn, N);
  k_scan23  <<<(N + 255) / 256, 256, 0, stream>>>(rs, bsum, N, E);
  k_csr_fill2<<<(E + 255) / 256, 256, 0, stream>>>(sdst, ssw, rank2, rs, dinv, epack, E);

  const int gy = (N + 127) / 128;

  // ---- layer 1: agg(featb)[N,64] @ W1[64,64] -> x1b (bf16) ----
  {
    int tot = N * (F / 8);
    k_aggregate_b<3><<<(tot + 255) / 256, 256, 0, stream>>>(featb, rs, epack, sn, aggh, N);
    dim3 g(1, gy);
    k_gemm_mfma<64, 64><<<g, 256, 0, stream>>>(aggh, w1h, b1, x1b, N, F);
  }
  // ---- layer 2: agg(x1b)[N,64] @ W2[64,128] -> x2b (bf16) ----
  {
    int tot = N * (F / 8);
    k_aggregate_b<3><<<(tot + 255) / 256, 256, 0, stream>>>(x1b, rs, epack, sn, aggh, N);
    dim3 g(1, gy);
    k_gemm_mfma<64, 128><<<g, 256, 0, stream>>>(aggh, w2h, b2, x2b, N, D2);
  }
  // ---- layer 3: agg(x2b)[N,128] @ W3[128,256] -> x3b (bf16) ----
  {
    int tot = N * (D2 / 8);
    k_aggregate_b<4><<<(tot + 255) / 256, 256, 0, stream>>>(x2b, rs, epack, sn, aggh, N);
    dim3 g(2, gy);
    k_gemm_mfma<128, 128><<<g, 256, 0, stream>>>(aggh, w3h, b3, x3b, N, D3);
  }

  // ---- pooling + head ----
  k_pool <<<(N + 63) / 64, C, 0, stream>>>(x3b, feature, pb, psum, gcnt, N, D3, F);
  {
    dim3 g((Hh + 255) / 256, B);
    k_fc1<<<g, 256, 0, stream>>>(psum, gcnt, Wf1, bf1, hid, C, Hh);
  }
  k_fc2  <<<B, 64, 0, stream>>>(hid, Wf2, bf2, out, Hh);
}

// Round 12
// 439.138 us; speedup vs baseline: 1.2095x; 1.0065x over previous
//
#include <hip/hip_runtime.h>
#include <cstdio>
#include <cstdint>

typedef _Float16 f16x8 __attribute__((ext_vector_type(8)));
typedef float f32x4 __attribute__((ext_vector_type(4)));

__device__ inline unsigned short f2bf(float f) {  // fp32 -> bf16 RNE
  unsigned u = __float_as_uint(f);
  u += 0x7fffu + ((u >> 16) & 1u);
  return (unsigned short)(u >> 16);
}
__device__ inline float bf2f(unsigned short h) {
  return __uint_as_float(((unsigned)h) << 16);
}
__device__ inline unsigned short f2h(float f) {   // fp32 -> fp16 RNE (bits)
  union { _Float16 h; unsigned short u; } cv;
  cv.h = (_Float16)f;
  return cv.u;
}

// ================= fused prep: zero psum/gcnt, feat->bf16, W->fp16^T ======

__global__ __launch_bounds__(256)
void k_prep(double* __restrict__ psum, float* __restrict__ gcnt,
            const float* __restrict__ feature, ushort* __restrict__ featb,
            const float* __restrict__ W1, ushort* __restrict__ w1h,
            const float* __restrict__ W2, ushort* __restrict__ w2h,
            const float* __restrict__ W3, ushort* __restrict__ w3h,
            int BC, int Bn, int NF, int F, int D2, int D3,
            int nB, int nC) {
  int b = blockIdx.x;
  int t = threadIdx.x;
  if (b < nB) {
    int i = b * 256 + t;
    if (i < BC) psum[i] = 0.0;
    if (i < Bn) gcnt[i] = 0.f;
  } else if (b < nB + nC) {
    int base = ((b - nB) * 256 + t) * 4;
    if (base < NF) {
      float4 v = *reinterpret_cast<const float4*>(feature + base);
      ushort4 h;
      h.x = f2bf(v.x); h.y = f2bf(v.y); h.z = f2bf(v.z); h.w = f2bf(v.w);
      *reinterpret_cast<ushort4*>(featb + base) = h;
    }
  } else {
    int idx = (b - nB - nC) * 256 + t;
    int s1 = F * F, s2 = s1 + F * D2, s3 = s2 + D2 * D3;
    if (idx < s1) {
      int k = idx / F, n = idx - k * F;
      w1h[(size_t)n * F + k] = f2h(W1[idx]);
    } else if (idx < s2) {
      int i2 = idx - s1; int k = i2 / D2, n = i2 - k * D2;
      w2h[(size_t)n * F + k] = f2h(W2[i2]);
    } else if (idx < s3) {
      int i3 = idx - s2; int k = i3 / D3, n = i3 - k * D3;
      w3h[(size_t)n * D2 + k] = f2h(W3[i3]);
    }
  }
}

// ================= sort-based CSR build (ZERO global atomics) =============
// Bucket sort by dst>>8 (256 nodes/bucket). EPB=4096 edges/block: per-bin
// runs ~10.5 edges -> sector amplification ~1.5x (R11's EPB=1024 gave runs
// of 2.6 edges -> 4.2x WRITE amplification, 52us).

#define EPB 4096

__global__ __launch_bounds__(256)
void k_bhist(const int* __restrict__ dst, int* __restrict__ H,
             int NB, int E) {
  __shared__ int hist[512];
  const int t = threadIdx.x;
  for (int i = t; i < NB; i += 256) hist[i] = 0;
  __syncthreads();
  const int base = blockIdx.x * EPB + t;
#pragma unroll
  for (int j = 0; j < EPB / 256; j++) {
    int e = base + 256 * j;
    if (e < E) atomicAdd(&hist[dst[e] >> 8], 1);
  }
  __syncthreads();
  for (int i = t; i < NB; i += 256) H[(size_t)blockIdx.x * NB + i] = hist[i];
}

// exclusive scan over T = NB*NBLK elems in bin-major order j=bin*NBLK+bi,
// reading block-major H[bi*NB+bin]; output S[j] (bin-major).
__global__ __launch_bounds__(256)
void k_bscan1(const int* __restrict__ H, int* __restrict__ S,
              int* __restrict__ bsum, int NB, int NBLK, int T) {
  __shared__ int sh[256];
  const int t = threadIdx.x;
  const int base = blockIdx.x * 1024;
  int v[4]; int s = 0;
#pragma unroll
  for (int j = 0; j < 4; j++) {
    int idx = base + t * 4 + j;
    if (idx < T) {
      int bin = idx / NBLK, bi = idx - bin * NBLK;
      v[j] = H[(size_t)bi * NB + bin];
    } else v[j] = 0;
    s += v[j];
  }
  sh[t] = s;
  __syncthreads();
  for (int off = 1; off < 256; off <<= 1) {
    int x = (t >= off) ? sh[t - off] : 0;
    __syncthreads();
    sh[t] += x;
    __syncthreads();
  }
  int run = sh[t] - s;
#pragma unroll
  for (int j = 0; j < 4; j++) {
    int idx = base + t * 4 + j;
    if (idx < T) S[idx] = run;
    run += v[j];
  }
  if (t == 255) bsum[blockIdx.x] = sh[255];
}

__global__ __launch_bounds__(256)
void k_bscan23(int* __restrict__ S, const int* __restrict__ bsum, int T) {
  __shared__ int spre;
  const int chunk = blockIdx.x >> 2;
  if (threadIdx.x == 0) {
    int pre = 0;
    for (int t = 0; t < chunk; t++) pre += bsum[t];
    spre = pre;
  }
  __syncthreads();
  int i = blockIdx.x * 256 + threadIdx.x;
  if (i < T) S[i] += spre;
}

// scatter edges into bucket-sorted order
__global__ __launch_bounds__(256)
void k_bscatter(const int* __restrict__ src, const int* __restrict__ dst,
                const float* __restrict__ ew, const int* __restrict__ S,
                int* __restrict__ sdst, int2* __restrict__ ssw,
                int NB, int NBLK, int E) {
  __shared__ int cnt[512];
  __shared__ int sbase[512];
  const int t = threadIdx.x, bi = blockIdx.x;
  for (int i = t; i < NB; i += 256) {
    cnt[i] = 0;
    sbase[i] = S[(size_t)i * NBLK + bi];
  }
  __syncthreads();
  const int base = bi * EPB + t;
#pragma unroll
  for (int j = 0; j < EPB / 256; j++) {
    int e = base + 256 * j;
    if (e < E) {
      int d = dst[e];
      int bin = d >> 8;
      int r = atomicAdd(&cnt[bin], 1);
      int pos = sbase[bin] + r;
      sdst[pos] = d;
      ssw[pos] = make_int2(src[e], __float_as_int(ew[e]));
    }
  }
}

// per-bucket pass A: node counts + fp32 weighted degree, coalesced write.
__global__ __launch_bounds__(256)
void k_bprocA(const int* __restrict__ sdst, const int2* __restrict__ ssw,
              const int* __restrict__ S, int* __restrict__ cntN,
              float* __restrict__ wsumN, int NB, int NBLK, int N, int E) {
  __shared__ int cnt[256];
  __shared__ float wsm[256];
  const int t = threadIdx.x, bin = blockIdx.x;
  cnt[t] = 0; wsm[t] = 0.f;
  __syncthreads();
  const int start = S[(size_t)bin * NBLK];
  const int end = (bin + 1 < NB) ? S[(size_t)(bin + 1) * NBLK] : E;
  for (int p = start + t; p < end; p += 256) {
    int ld = sdst[p] & 255;
    atomicAdd(&cnt[ld], 1);
    atomicAdd(&wsm[ld], __int_as_float(ssw[p].y));
  }
  __syncthreads();
  int n = bin * 256 + t;
  if (n < N) { cntN[n] = cnt[t]; wsumN[n] = wsm[t]; }
}

// scan of cntN -> rs; dinv/selfnorm fused (deg = 1 + wsum)
__global__ __launch_bounds__(256)
void k_scan1(const int* __restrict__ cntN, const float* __restrict__ wsumN,
             int* __restrict__ rs, int* __restrict__ bsum,
             float* __restrict__ dinv, float* __restrict__ sn, int N) {
  __shared__ int sh[256];
  const int t = threadIdx.x;
  const int base = blockIdx.x * 1024;
  int v[4]; int s = 0;
#pragma unroll
  for (int j = 0; j < 4; j++) {
    int idx = base + t * 4 + j;
    if (idx < N) {
      v[j] = cntN[idx];
      double deg = 1.0 + (double)wsumN[idx];
      float r = (float)(1.0 / sqrt(deg));
      dinv[idx] = r;
      sn[idx] = r * r;
    } else v[j] = 0;
    s += v[j];
  }
  sh[t] = s;
  __syncthreads();
  for (int off = 1; off < 256; off <<= 1) {
    int x = (t >= off) ? sh[t - off] : 0;
    __syncthreads();
    sh[t] += x;
    __syncthreads();
  }
  int run = sh[t] - s;
#pragma unroll
  for (int j = 0; j < 4; j++) {
    int idx = base + t * 4 + j;
    if (idx < N) rs[idx] = run;
    run += v[j];
  }
  if (t == 255) bsum[blockIdx.x] = sh[255];
}

__global__ __launch_bounds__(256)
void k_scan23(int* __restrict__ rs, const int* __restrict__ bsum, int N, int E) {
  __shared__ int spre;
  const int chunk = blockIdx.x >> 2;
  if (threadIdx.x == 0) {
    int pre = 0;
    for (int t = 0; t < chunk; t++) pre += bsum[t];
    spre = pre;
  }
  __syncthreads();
  int i = blockIdx.x * 256 + threadIdx.x;
  if (i < N) rs[i] += spre;
  if (i == 0) rs[N] = E;   // row-end sentinel
}

// per-bucket pass B: recompute LDS ranks, write epack directly at
// rs[d]+rank (bucket-local ~24KB region). Replaces csr_fill2 + rank2.
__global__ __launch_bounds__(256)
void k_bprocB(const int* __restrict__ sdst, const int2* __restrict__ ssw,
              const int* __restrict__ S, const int* __restrict__ rs,
              const float* __restrict__ dinv,
              int2* __restrict__ epack, int NB, int NBLK, int N, int E) {
  __shared__ int cnt[256];
  __shared__ float sdv[256];
  __shared__ int srs[256];
  const int t = threadIdx.x, bin = blockIdx.x;
  cnt[t] = 0;
  int n = bin * 256 + t;
  sdv[t] = (n < N) ? dinv[n] : 0.f;
  srs[t] = (n < N) ? rs[n] : 0;
  __syncthreads();
  const int start = S[(size_t)bin * NBLK];
  const int end = (bin + 1 < NB) ? S[(size_t)(bin + 1) * NBLK] : E;
  for (int p = start + t; p < end; p += 256) {
    int d = sdst[p];
    int ld = d & 255;
    int2 sw = ssw[p];
    int r = atomicAdd(&cnt[ld], 1);
    float w = dinv[sw.x] * __int_as_float(sw.y) * sdv[ld];
    epack[srs[ld] + r] = make_int2(sw.x, __float_as_int(w));
  }
}

// ================= CSR gather aggregation (bf16 in, fp16 out) ======

__device__ inline void bf8_fma(const int4 v, float w, float* acc) {
  acc[0] = fmaf(__uint_as_float((unsigned)v.x << 16), w, acc[0]);
  acc[1] = fmaf(__uint_as_float((unsigned)v.x & 0xffff0000u), w, acc[1]);
  acc[2] = fmaf(__uint_as_float((unsigned)v.y << 16), w, acc[2]);
  acc[3] = fmaf(__uint_as_float((unsigned)v.y & 0xffff0000u), w, acc[3]);
  acc[4] = fmaf(__uint_as_float((unsigned)v.z << 16), w, acc[4]);
  acc[5] = fmaf(__uint_as_float((unsigned)v.z & 0xffff0000u), w, acc[5]);
  acc[6] = fmaf(__uint_as_float((unsigned)v.w << 16), w, acc[6]);
  acc[7] = fmaf(__uint_as_float((unsigned)v.w & 0xffff0000u), w, acc[7]);
}

template<int LOG2L>
__global__ __launch_bounds__(256)
void k_aggregate_b(const ushort* __restrict__ Xb, const int* __restrict__ rs,
                   const int2* __restrict__ epack, const float* __restrict__ sn,
                   ushort* __restrict__ AH, int N) {
  const int t = blockIdx.x * blockDim.x + threadIdx.x;
  const int row = t >> LOG2L;
  if (row >= N) return;
  const int L = 1 << LOG2L;
  const int D = L << 3;
  const int c = (t & (L - 1)) << 3;

  float acc[8];
  {
    int4 v = *reinterpret_cast<const int4*>(Xb + (size_t)row * D + c);
    float s = sn[row];
    acc[0] = s * __uint_as_float((unsigned)v.x << 16);
    acc[1] = s * __uint_as_float((unsigned)v.x & 0xffff0000u);
    acc[2] = s * __uint_as_float((unsigned)v.y << 16);
    acc[3] = s * __uint_as_float((unsigned)v.y & 0xffff0000u);
    acc[4] = s * __uint_as_float((unsigned)v.z << 16);
    acc[5] = s * __uint_as_float((unsigned)v.z & 0xffff0000u);
    acc[6] = s * __uint_as_float((unsigned)v.w << 16);
    acc[7] = s * __uint_as_float((unsigned)v.w & 0xffff0000u);
  }
  const int p0 = rs[row], pe = rs[row + 1];
  int i = p0;
  if ((i & 1) && i < pe) {
    int2 e = epack[i];
    int4 v = *reinterpret_cast<const int4*>(Xb + (size_t)e.x * D + c);
    bf8_fma(v, __int_as_float(e.y), acc);
    i++;
  }
  for (; i + 2 <= pe; i += 2) {
    int4 e2 = *reinterpret_cast<const int4*>(&epack[i]);
    int4 v0 = *reinterpret_cast<const int4*>(Xb + (size_t)e2.x * D + c);
    int4 v1 = *reinterpret_cast<const int4*>(Xb + (size_t)e2.z * D + c);
    bf8_fma(v0, __int_as_float(e2.y), acc);
    bf8_fma(v1, __int_as_float(e2.w), acc);
  }
  if (i < pe) {
    int2 e = epack[i];
    int4 v = *reinterpret_cast<const int4*>(Xb + (size_t)e.x * D + c);
    bf8_fma(v, __int_as_float(e.y), acc);
  }
  ushort h[8];
#pragma unroll
  for (int j = 0; j < 8; j++) h[j] = f2h(acc[j]);
  size_t o = (size_t)row * D + c;
  *reinterpret_cast<ushort4*>(AH + o)     = make_ushort4(h[0], h[1], h[2], h[3]);
  *reinterpret_cast<ushort4*>(AH + o + 4) = make_ushort4(h[4], h[5], h[6], h[7]);
}

// ================= fp16 MFMA GEMM: Y = relu(A @ W + b), bf16 out ==========

template<int KT, int NT>
__global__ __launch_bounds__(256)
void k_gemm_mfma(const ushort* __restrict__ Ah, const ushort* __restrict__ Bh,
                 const float* __restrict__ bias, ushort* __restrict__ Y,
                 int N, int D) {
  constexpr int PK = 72;
  __shared__ __align__(16) ushort sAh[128 * PK];
  __shared__ __align__(16) ushort sBh[NT * PK];
  const int t = threadIdx.x;
  const int wave = t >> 6, lane = t & 63;
  const int quad = lane >> 4, l16 = lane & 15;
  const int m0 = blockIdx.y * 128;
  const int n0 = blockIdx.x * NT;

  f32x4 acc[2][NT / 16];
#pragma unroll
  for (int mi = 0; mi < 2; mi++)
#pragma unroll
    for (int ni = 0; ni < NT / 16; ni++) acc[mi][ni] = (f32x4){0.f, 0.f, 0.f, 0.f};

  for (int k0 = 0; k0 < KT; k0 += 64) {
    if (k0) __syncthreads();
#pragma unroll
    for (int it = 0; it < 4; it++) {
      int c = t + 256 * it;
      int row = c >> 3, kc = (c & 7) << 3;
      int gr = m0 + row; if (gr >= N) gr = N - 1;
      *reinterpret_cast<int4*>(&sAh[row * PK + kc]) =
          *reinterpret_cast<const int4*>(Ah + (size_t)gr * KT + k0 + kc);
    }
#pragma unroll
    for (int it = 0; it < NT / 32; it++) {
      int c = t + 256 * it;
      int row = c >> 3, kc = (c & 7) << 3;
      *reinterpret_cast<int4*>(&sBh[row * PK + kc]) =
          *reinterpret_cast<const int4*>(Bh + (size_t)(n0 + row) * KT + k0 + kc);
    }
    __syncthreads();
#pragma unroll
    for (int ks = 0; ks < 2; ks++) {
      const int kk = ks * 32 + quad * 8;
      f16x8 aH[2];
#pragma unroll
      for (int mi = 0; mi < 2; mi++) {
        int r = wave * 32 + mi * 16 + l16;
        aH[mi] = *reinterpret_cast<const f16x8*>(&sAh[r * PK + kk]);
      }
#pragma unroll
      for (int ni = 0; ni < NT / 16; ni++) {
        int r = ni * 16 + l16;
        f16x8 bH = *reinterpret_cast<const f16x8*>(&sBh[r * PK + kk]);
#pragma unroll
        for (int mi = 0; mi < 2; mi++)
          acc[mi][ni] = __builtin_amdgcn_mfma_f32_16x16x32_f16(aH[mi], bH, acc[mi][ni], 0, 0, 0);
      }
    }
  }
#pragma unroll
  for (int mi = 0; mi < 2; mi++) {
    int rb = m0 + wave * 32 + mi * 16 + quad * 4;
#pragma unroll
    for (int ni = 0; ni < NT / 16; ni++) {
      int col = n0 + ni * 16 + l16;
      float bv = bias[col];
#pragma unroll
      for (int r = 0; r < 4; r++) {
        int row = rb + r;
        if (row < N)
          Y[(size_t)row * D + col] = f2bf(fmaxf(acc[mi][ni][r] + bv, 0.f));
      }
    }
  }
}

// ================= pooling (sorted protein_batch; count fused c==0) =======

__global__ void k_pool(const ushort* __restrict__ X3b, const float* __restrict__ feat,
                       const int* __restrict__ pb, double* __restrict__ psum,
                       float* __restrict__ gcnt, int N, int D3, int F) {
  const int c = threadIdx.x;
  const int C = D3 + F;
  int i0 = blockIdx.x * 64;
  if (i0 >= N) return;
  int iend = i0 + 64; if (iend > N) iend = N;
  double acc = 0.0;
  float cacc = 0.f;
  int cur = pb[i0];
  for (int i = i0; i < iend; i++) {
    int b = pb[i];
    if (b != cur) {
      atomicAdd(&psum[(size_t)cur * C + c], acc);
      if (c == 0) atomicAdd(&gcnt[cur], cacc);
      acc = 0.0; cacc = 0.f; cur = b;
    }
    float v;
    if (c < D3) v = bf2f(X3b[(size_t)i * D3 + c]);
    else        v = feat[(size_t)i * F + (c - D3)];
    acc += (double)v;
    cacc += 1.f;
  }
  atomicAdd(&psum[(size_t)cur * C + c], acc);
  if (c == 0) atomicAdd(&gcnt[cur], cacc);
}

// ================= FC head (gc normalization fused into fc1) ==============

__global__ __launch_bounds__(256)
void k_fc1(const double* __restrict__ psum, const float* __restrict__ cnt,
           const float* __restrict__ Wf1, const float* __restrict__ bf1,
           float* __restrict__ hidden, int C, int Hh) {
  const int b = blockIdx.y;
  __shared__ float gcs[384];
  float invc = 1.f / fmaxf(cnt[b], 1.f);
  for (int c = threadIdx.x; c < C; c += 256)
    gcs[c] = (float)psum[(size_t)b * C + c] * invc;
  __syncthreads();
  const int j = blockIdx.x * 256 + threadIdx.x;
  if (j >= Hh) return;
  const float* w = Wf1 + j;
  float a0 = 0.f, a1 = 0.f, a2 = 0.f, a3 = 0.f;
  int c = 0;
  for (; c + 4 <= C; c += 4) {
    a0 = fmaf(gcs[c + 0], w[(size_t)(c + 0) * Hh], a0);
    a1 = fmaf(gcs[c + 1], w[(size_t)(c + 1) * Hh], a1);
    a2 = fmaf(gcs[c + 2], w[(size_t)(c + 2) * Hh], a2);
    a3 = fmaf(gcs[c + 3], w[(size_t)(c + 3) * Hh], a3);
  }
  for (; c < C; c++) a0 = fmaf(gcs[c], w[(size_t)c * Hh], a0);
  float r = ((a0 + a1) + (a2 + a3)) + bf1[j];
  hidden[(size_t)b * Hh + j] = fmaxf(r, 0.f);
}

__global__ void k_fc2(const float* __restrict__ hidden, const float* __restrict__ Wf2,
                      const float* __restrict__ bf2, float* __restrict__ out, int Hh) {
  int b = blockIdx.x;
  int lane = threadIdx.x;  // 64
  double s = 0.0;
  for (int j = lane; j < Hh; j += 64) s += (double)hidden[(size_t)b * Hh + j] * (double)Wf2[j];
#pragma unroll
  for (int off = 32; off > 0; off >>= 1) s += __shfl_down(s, off);
  if (lane == 0) out[b] = (float)s + bf2[0];
}

// ================= launch =================

extern "C" void kernel_launch(void* const* d_in, const int* in_sizes, int n_in,
                              void* d_out, int out_size, void* d_ws, size_t ws_size,
                              hipStream_t stream) {
  const float* feature = (const float*)d_in[0];
  const int*   eidx    = (const int*)  d_in[1];
  const float* weight  = (const float*)d_in[2];
  const int*   pb      = (const int*)  d_in[3];
  const float* W1  = (const float*)d_in[4];
  const float* b1  = (const float*)d_in[5];
  const float* W2  = (const float*)d_in[6];
  const float* b2  = (const float*)d_in[7];
  const float* W3  = (const float*)d_in[8];
  const float* b3  = (const float*)d_in[9];
  const float* Wf1 = (const float*)d_in[10];
  const float* bf1 = (const float*)d_in[11];
  const float* Wf2 = (const float*)d_in[12];
  const float* bf2 = (const float*)d_in[13];

  const int F  = in_sizes[5];          // 64
  const int D2 = in_sizes[7];          // 128
  const int D3 = in_sizes[9];          // 256
  const int Hh = in_sizes[11];         // 1024
  const int N  = in_sizes[0] / F;      // 100000
  const int E  = in_sizes[1] / 2;      // 1200000
  const int B  = out_size;             // 256
  const int C  = D3 + F;               // 320

  const int* srcp = eidx;
  const int* dstp = eidx + E;

  const int NB   = (N + 255) / 256;        // buckets (<=512)
  const int NBLK = (E + EPB - 1) / EPB;    // edge blocks
  const int T    = NB * NBLK;              // scan length
  const int nscanb = (T + 1023) / 1024;
  const int nscan  = (N + 1023) / 1024;

  auto al = [](size_t x) { return (x + 255) & ~(size_t)255; };
  size_t off = 0;
  auto alloc = [&](size_t bytes) { size_t o = off; off += al(bytes); return o; };
  size_t o_H     = alloc((size_t)T * 4);
  size_t o_S     = alloc((size_t)T * 4);
  size_t o_bsb   = alloc((size_t)nscanb * 4);
  size_t o_sdst  = alloc((size_t)E * 4);
  size_t o_ssw   = alloc((size_t)E * 8);
  size_t o_cntN  = alloc((size_t)N * 4);
  size_t o_wsumN = alloc((size_t)N * 4);
  size_t o_dinv  = alloc((size_t)N * 4);
  size_t o_sn    = alloc((size_t)N * 4);
  size_t o_rs    = alloc((size_t)(N + 1) * 4);
  size_t o_bsum  = alloc((size_t)nscan * 4);
  size_t o_epack = alloc((size_t)E * 8);
  size_t o_featb = alloc((size_t)N * F  * 2);
  size_t o_x1b   = alloc((size_t)N * F  * 2);
  size_t o_x2b   = alloc((size_t)N * D2 * 2);
  size_t o_x3b   = alloc((size_t)N * D3 * 2);
  size_t o_aggh  = alloc((size_t)N * D2 * 2);   // fp16 (max K = 128)
  size_t o_w1h   = alloc((size_t)F  * F  * 2);
  size_t o_w2h   = alloc((size_t)F  * D2 * 2);
  size_t o_w3h   = alloc((size_t)D2 * D3 * 2);
  size_t o_psum  = alloc((size_t)B * C * 8);
  size_t o_gcnt  = alloc((size_t)B * 4);
  size_t o_hid   = alloc((size_t)B * Hh * 4);
  if (off > ws_size) {
    fprintf(stderr, "kernel_launch: workspace too small: need %zu, have %zu\n", off, ws_size);
    return;
  }

  char* ws = (char*)d_ws;
  int*    H     = (int*)  (ws + o_H);
  int*    S     = (int*)  (ws + o_S);
  int*    bsb   = (int*)  (ws + o_bsb);
  int*    sdst  = (int*)  (ws + o_sdst);
  int2*   ssw   = (int2*) (ws + o_ssw);
  int*    cntN  = (int*)  (ws + o_cntN);
  float*  wsumN = (float*)(ws + o_wsumN);
  float*  dinv  = (float*)(ws + o_dinv);
  float*  sn    = (float*)(ws + o_sn);
  int*    rs    = (int*)  (ws + o_rs);
  int*    bsum  = (int*)  (ws + o_bsum);
  int2*   epack = (int2*) (ws + o_epack);
  ushort* featb = (ushort*)(ws + o_featb);
  ushort* x1b   = (ushort*)(ws + o_x1b);
  ushort* x2b   = (ushort*)(ws + o_x2b);
  ushort* x3b   = (ushort*)(ws + o_x3b);
  ushort* aggh  = (ushort*)(ws + o_aggh);
  ushort* w1h   = (ushort*)(ws + o_w1h);
  ushort* w2h   = (ushort*)(ws + o_w2h);
  ushort* w3h   = (ushort*)(ws + o_w3h);
  double* psum  = (double*)(ws + o_psum);
  float*  gcnt  = (float*)(ws + o_gcnt);
  float*  hid   = (float*)(ws + o_hid);
  float*  out   = (float*)d_out;

  // ---- fused prep ----
  const int BC = B * C, NF = N * F;
  const int nB = (BC + 255) / 256;
  const int nC = (NF / 4 + 255) / 256;
  const int nD = (F * F + F * D2 + D2 * D3 + 255) / 256;
  k_prep<<<nB + nC + nD, 256, 0, stream>>>(
      psum, gcnt, feature, featb, W1, w1h, W2, w2h, W3, w3h,
      BC, B, NF, F, D2, D3, nB, nC);

  // ---- sort-based CSR build (zero global atomics) ----
  k_bhist   <<<NBLK, 256, 0, stream>>>(dstp, H, NB, E);
  k_bscan1  <<<nscanb, 256, 0, stream>>>(H, S, bsb, NB, NBLK, T);
  k_bscan23 <<<(T + 255) / 256, 256, 0, stream>>>(S, bsb, T);
  k_bscatter<<<NBLK, 256, 0, stream>>>(srcp, dstp, weight, S, sdst, ssw, NB, NBLK, E);
  k_bprocA  <<<NB, 256, 0, stream>>>(sdst, ssw, S, cntN, wsumN, NB, NBLK, N, E);
  k_scan1   <<<nscan, 256, 0, stream>>>(cntN, wsumN, rs, bsum, dinv, sn, N);
  k_scan23  <<<(N + 255) / 256, 256, 0, stream>>>(rs, bsum, N, E);
  k_bprocB  <<<NB, 256, 0, stream>>>(sdst, ssw, S, rs, dinv, epack, NB, NBLK, N, E);

  const int gy = (N + 127) / 128;

  // ---- layer 1: agg(featb)[N,64] @ W1[64,64] -> x1b (bf16) ----
  {
    int tot = N * (F / 8);
    k_aggregate_b<3><<<(tot + 255) / 256, 256, 0, stream>>>(featb, rs, epack, sn, aggh, N);
    dim3 g(1, gy);
    k_gemm_mfma<64, 64><<<g, 256, 0, stream>>>(aggh, w1h, b1, x1b, N, F);
  }
  // ---- layer 2: agg(x1b)[N,64] @ W2[64,128] -> x2b (bf16) ----
  {
    int tot = N * (F / 8);
    k_aggregate_b<3><<<(tot + 255) / 256, 256, 0, stream>>>(x1b, rs, epack, sn, aggh, N);
    dim3 g(1, gy);
    k_gemm_mfma<64, 128><<<g, 256, 0, stream>>>(aggh, w2h, b2, x2b, N, D2);
  }
  // ---- layer 3: agg(x2b)[N,128] @ W3[128,256] -> x3b (bf16) ----
  {
    int tot = N * (D2 / 8);
    k_aggregate_b<4><<<(tot + 255) / 256, 256, 0, stream>>>(x2b, rs, epack, sn, aggh, N);
    dim3 g(2, gy);
    k_gemm_mfma<128, 128><<<g, 256, 0, stream>>>(aggh, w3h, b3, x3b, N, D3);
  }

  // ---- pooling + head ----
  k_pool <<<(N + 63) / 64, C, 0, stream>>>(x3b, feature, pb, psum, gcnt, N, D3, F);
  {
    dim3 g((Hh + 255) / 256, B);
    k_fc1<<<g, 256, 0, stream>>>(psum, gcnt, Wf1, bf1, hid, C, Hh);
  }
  k_fc2  <<<B, 64, 0, stream>>>(hid, Wf2, bf2, out, Hh);
}